// Round 10
// baseline (212.605 us; speedup 1.0000x reference)
//
#include <hip/hip_runtime.h>
#include <hip/hip_bf16.h>

typedef unsigned short u16;
typedef __attribute__((ext_vector_type(8))) __bf16 v8bf;
typedef __attribute__((ext_vector_type(4))) float v4f;

#define DEVINL __device__ __forceinline__

DEVINL u16 f2bf(float f) {
  union { float f; unsigned u; } v; v.f = f;
  unsigned u = v.u;
  return (u16)((u + 0x7FFFu + ((u >> 16) & 1u)) >> 16);  // RNE
}
DEVINL float bf2f(u16 b) {
  union { unsigned u; float f; } v; v.u = ((unsigned)b) << 16;
  return v.f;
}

// async global->LDS, 16B per lane; dest is wave-uniform base + lane*16
DEVINL void async16(const void* g, void* l) {
  __builtin_amdgcn_global_load_lds(
      (__attribute__((address_space(1))) void*)(g),
      (__attribute__((address_space(3))) void*)(l), 16, 0, 0);
}

// ---------------- merged precompute ----------------
DEVINL void f2b_body(const float* __restrict__ src, u16* __restrict__ dst, int base) {
  int i = base + threadIdx.x * 4;
  float4 v = *(const float4*)(src + i);
  unsigned lo = (unsigned)f2bf(v.x) | ((unsigned)f2bf(v.y) << 16);
  unsigned hi = (unsigned)f2bf(v.z) | ((unsigned)f2bf(v.w) << 16);
  uint2 o; o.x = lo; o.y = hi;
  *(uint2*)(dst + i) = o;
}

// 64x64 transpose+convert tile: src fp32 [R][C] -> dst bf16 [C][R]
DEVINL void tr64(u16 (*t)[66], const float* __restrict__ src,
                 u16* __restrict__ dst, int R, int C, int bx, int by) {
  int r0 = by * 64, c0 = bx * 64;
  int tx = threadIdx.x & 15, ty = threadIdx.x >> 4;  // 16x16 threads
#pragma unroll
  for (int i = 0; i < 4; ++i) {
    int rr = ty + i * 16;
    float4 v = *(const float4*)(src + (long)(r0 + rr) * C + c0 + tx * 4);
    u16* d = &t[rr][tx * 4];
    d[0] = f2bf(v.x); d[1] = f2bf(v.y); d[2] = f2bf(v.z); d[3] = f2bf(v.w);
  }
  __syncthreads();
#pragma unroll
  for (int i = 0; i < 4; ++i) {
    int cc = ty + i * 16;
    ushort4 o;
    o.x = t[tx * 4 + 0][cc]; o.y = t[tx * 4 + 1][cc];
    o.z = t[tx * 4 + 2][cc]; o.w = t[tx * 4 + 3][cc];
    *(ushort4*)(dst + (long)(c0 + cc) * R + r0 + tx * 4) = o;
  }
}

__global__ __launch_bounds__(256) void k_prep(
    const float* __restrict__ x, const float* __restrict__ ew2,
    const float* __restrict__ ew1, const float* __restrict__ dw1,
    const float* __restrict__ dw2, const float* __restrict__ lw1,
    const float* __restrict__ bw1, const float* __restrict__ pw1,
    const float* __restrict__ pw2,
    const float* __restrict__ eb1, const float* __restrict__ lb1,
    const float* __restrict__ bb1,
    u16* __restrict__ xb, u16* __restrict__ ew2b, u16* __restrict__ ew1tf,
    u16* __restrict__ dw1t, u16* __restrict__ dw2t,
    u16* __restrict__ pw1t, u16* __restrict__ pw2t,
    float* __restrict__ ebcat) {
  __shared__ u16 tile[64][66];
  int b = blockIdx.x;
  if (b < 2048) { f2b_body(x, xb, b * 1024); return; }
  b -= 2048;
  if (b < 3200) { f2b_body(ew2, ew2b, b * 1024); return; }
  b -= 3200;
  if (b < 3200) {
    int e = b >> 6, t = b & 63;
    tr64(tile, ew1 + (long)e * 1024 * 256, ew1tf + (long)e * 256 * 1024,
         1024, 256, t & 3, t >> 2);
    return;
  }
  b -= 3200;
  if (b < 1600) {
    tr64(tile, dw1, dw1t, 12800, 512, b & 7, b >> 3);
    return;
  }
  b -= 1600;
  if (b < 32) {
    tr64(tile, dw2, dw2t, 512, 256, b & 3, b >> 2);
    return;
  }
  b -= 32;
  if (b < 64) {
    tr64(tile, lw1, ew1tf + (long)12800 * 1024, 1024, 256, b & 3, b >> 2);
    return;
  }
  b -= 64;
  if (b < 64) {
    tr64(tile, bw1, ew1tf + (long)13056 * 1024, 1024, 256, b & 3, b >> 2);
    return;
  }
  b -= 64;
  if (b < 16) {
    tr64(tile, pw1, pw1t, 256, 256, b & 3, b >> 2);
    return;
  }
  b -= 16;
  if (b < 16) {
    tr64(tile, pw2, pw2t, 256, 256, b & 3, b >> 2);
    return;
  }
  b -= 16;
  {
    int i = b * 256 + threadIdx.x;
    float v;
    if (i < 12800) v = eb1[i];
    else if (i < 13056) v = lb1[i - 12800];
    else v = bb1[i - 13056];
    ebcat[i] = v;
  }
}

// ---------------- 128x128 MFMA GEMM body (shared; tid-parameterized, 256 lanes) ----------------
DEVINL void gemm128_body(int tid, u16* __restrict__ sA, u16* __restrict__ sB,
    int bx, int by, int z,
    const u16* __restrict__ A, int lda, long aBatch,
    const u16* __restrict__ B, int ldb, long bBatch,   // B is Bt: [N][K]
    void* __restrict__ Cp, int ldc, long cBatch,
    int K,
    const float* __restrict__ bias, long biasBatch,
    const float* __restrict__ rowscale, int flags) {
  const int w = tid >> 6, l = tid & 63;
  const u16* Ab = A + (long)z * aBatch + (long)by * 128 * lda;
  const u16* Bb = B + (long)z * bBatch + (long)bx * 128 * ldb;
  const int ldaB = lda * 2, ldbB = ldb * 2;
  const int wm = w >> 1, wn = w & 1;
  const int r = l & 15, kq = l >> 4;

  const int f0 = w * 1024 + l * 16;
  const int f1 = f0 + 4096;
  const int row0 = f0 >> 6, cb0 = f0 & 63;
  const int row1 = f1 >> 6, cb1 = f1 & 63;
  const int seg0 = w * 1024, seg1 = seg0 + 4096;

  v4f acc[4][4];
#pragma unroll
  for (int m = 0; m < 4; ++m)
#pragma unroll
    for (int n = 0; n < 4; ++n) acc[m][n] = v4f{0.f, 0.f, 0.f, 0.f};

  const char* gA = (const char*)Ab;
  const char* gB = (const char*)Bb;
  const int nkt = K / 32;

  async16(gA + (long)row0 * ldaB + cb0, (char*)sA + seg0);
  async16(gA + (long)row1 * ldaB + cb1, (char*)sA + seg1);
  async16(gB + (long)row0 * ldbB + cb0, (char*)sB + seg0);
  async16(gB + (long)row1 * ldbB + cb1, (char*)sB + seg1);
  __syncthreads();

  for (int kt = 0; kt < nkt; ++kt) {
    const int cur = kt & 1;
    if (kt + 1 < nkt) {
      const long ko = (long)(kt + 1) * 64;
      async16(gA + ko + (long)row0 * ldaB + cb0, (char*)sA + (cur ^ 1) * 8192 + seg0);
      async16(gA + ko + (long)row1 * ldaB + cb1, (char*)sA + (cur ^ 1) * 8192 + seg1);
      async16(gB + ko + (long)row0 * ldbB + cb0, (char*)sB + (cur ^ 1) * 8192 + seg0);
      async16(gB + ko + (long)row1 * ldbB + cb1, (char*)sB + (cur ^ 1) * 8192 + seg1);
    }
    v8bf af[4], bfr[4];
#pragma unroll
    for (int m = 0; m < 4; ++m)
      af[m] = *(const v8bf*)&sA[cur * 4096 + (wm * 64 + m * 16 + r) * 32 + kq * 8];
#pragma unroll
    for (int n = 0; n < 4; ++n)
      bfr[n] = *(const v8bf*)&sB[cur * 4096 + (wn * 64 + n * 16 + r) * 32 + kq * 8];
#pragma unroll
    for (int m = 0; m < 4; ++m)
#pragma unroll
      for (int n = 0; n < 4; ++n)
        acc[m][n] = __builtin_amdgcn_mfma_f32_16x16x32_bf16(af[m], bfr[n], acc[m][n], 0, 0, 0);
    __syncthreads();
  }

  const float* bz = bias ? (bias + (long)z * biasBatch) : nullptr;
  const long rowBase = (long)by * 128 + wm * 64 + kq * 4;
  const int colBase = bx * 128 + wn * 64 + r;
  float* Cf = (float*)Cp + (long)z * cBatch;
  u16* Ch = (u16*)Cp + (long)z * cBatch;
#pragma unroll
  for (int m = 0; m < 4; ++m) {
#pragma unroll
    for (int n = 0; n < 4; ++n) {
      const int col = colBase + n * 16;
      const float bv = bz ? bz[col] : 0.f;
#pragma unroll
      for (int i = 0; i < 4; ++i) {
        const long row = rowBase + m * 16 + i;
        float v = acc[m][n][i] + bv;
        if (flags & 1) v = fmaxf(v, 0.f);
        if (rowscale) v *= rowscale[row];
        const long idx = row * ldc + col;
        if (flags & 2) Cf[idx] = v;
        else Ch[idx] = f2bf(v);
      }
    }
  }
}

__global__ __launch_bounds__(256) void k_gemm(
    const u16* __restrict__ A, int lda, long aBatch,
    const u16* __restrict__ B, int ldb, long bBatch,
    void* __restrict__ Cp, int ldc, long cBatch,
    int K,
    const float* __restrict__ bias, long biasBatch,
    const float* __restrict__ rowscale, int flags) {
  __shared__ __align__(16) u16 sA[2 * 4096];
  __shared__ __align__(16) u16 sB[2 * 4096];
  gemm128_body(threadIdx.x, sA, sB, blockIdx.x, blockIdx.y, blockIdx.z,
               A, lda, aBatch, B, ldb, bBatch, Cp, ldc, cBatch, K,
               bias, biasBatch, rowscale, flags);
}

// ======= combined dispatch: 256^2 8-phase GEMM1 blocks + wft/bias filler blocks =======
#define LDS_T(buf, op) (smem + ((buf) * 2 + (op)) * 16384)

#define READ_A(buf, mh) do {                                                   \
  const char* _t = (const char*)LDS_T(buf, 0);                                 \
  _Pragma("unroll") for (int m = 0; m < 4; ++m)                                \
    _Pragma("unroll") for (int kk = 0; kk < 2; ++kk)                           \
      a[m][kk] = *(const v8bf*)(_t +                                           \
        (wm * 128 + (mh) * 64 + m * 16 + r15) * 128 +                          \
        ((kk * 64 + kq * 16) ^ (swr << 4)));                                   \
} while (0)

#define READ_B(buf, nh, br) do {                                               \
  const char* _t = (const char*)LDS_T(buf, 1);                                 \
  _Pragma("unroll") for (int n = 0; n < 2; ++n)                                \
    _Pragma("unroll") for (int kk = 0; kk < 2; ++kk)                           \
      br[n][kk] = *(const v8bf*)(_t +                                          \
        (wn * 64 + (nh) * 32 + n * 16 + r15) * 128 +                          \
        ((kk * 64 + kq * 16) ^ (swr << 4)));                                   \
} while (0)

#define MMA(mh, nh, br) do {                                                   \
  _Pragma("unroll") for (int kk = 0; kk < 2; ++kk)                             \
    _Pragma("unroll") for (int m = 0; m < 4; ++m)                              \
      _Pragma("unroll") for (int n = 0; n < 2; ++n)                            \
        acc[(mh) * 4 + m][(nh) * 2 + n] =                                      \
          __builtin_amdgcn_mfma_f32_16x16x32_bf16(                             \
            a[m][kk], br[n][kk], acc[(mh) * 4 + m][(nh) * 2 + n], 0, 0, 0);    \
} while (0)

#define BAR() __builtin_amdgcn_s_barrier()
#define PRIO1() __builtin_amdgcn_s_setprio(1)
#define PRIO0() __builtin_amdgcn_s_setprio(0)
#define VM6() asm volatile("s_waitcnt vmcnt(6)" ::: "memory")
#define VM0() asm volatile("s_waitcnt vmcnt(0)" ::: "memory")
#define LGKM0() asm volatile("s_waitcnt lgkmcnt(0)" ::: "memory")

__global__ __launch_bounds__(512, 2) void k_gemm256(
    const u16* __restrict__ A, int lda,
    const u16* __restrict__ B, int ldb,
    void* __restrict__ Cp, int ldc,
    int K, int NX,
    const float* __restrict__ bias, int flags,
    const u16* __restrict__ dw1t, const u16* __restrict__ ew2b,
    u16* __restrict__ Wft,
    const float* __restrict__ eb2, const float* __restrict__ db1,
    float* __restrict__ biasf, int ngemm1) {
  __shared__ __align__(16) u16 smem[2 * 2 * 16384];  // 128 KiB

  const int lin = blockIdx.x;
  const int tid = threadIdx.x;

  if (lin >= ngemm1) {
    int fb = lin - ngemm1;
    int sub = tid >> 8, t = tid & 255;
    if (fb < 200) {
      int tt = fb * 2 + sub;
      int bx = tt & 1, by = (tt >> 1) & 3, z = tt >> 3;
      u16* base = smem + sub * 16384;
      gemm128_body(t, base, base + 8192, bx, by, z,
                   dw1t, 12800, 256, ew2b, 256, (long)256 * 256,
                   Wft, 12800, 256, 256, nullptr, 0, nullptr, 0);
      return;
    }
    int r = (fb - 200) * 2 + sub;
    const u16* row = dw1t + (long)r * 12800;
    float s = 0.f;
    for (int c = t; c < 1600; c += 256) {
      ushort4 a0 = *(const ushort4*)(row + c * 8);
      ushort4 a1 = *(const ushort4*)(row + c * 8 + 4);
      float4 e0 = *(const float4*)(eb2 + c * 8);
      float4 e1 = *(const float4*)(eb2 + c * 8 + 4);
      s += bf2f(a0.x) * e0.x + bf2f(a0.y) * e0.y + bf2f(a0.z) * e0.z + bf2f(a0.w) * e0.w
         + bf2f(a1.x) * e1.x + bf2f(a1.y) * e1.y + bf2f(a1.z) * e1.z + bf2f(a1.w) * e1.w;
    }
    float* red = (float*)smem + sub * 256;
    red[t] = s;
    __syncthreads();
    for (int off = 128; off > 0; off >>= 1) {
      if (t < off) red[t] += red[t + off];
      __syncthreads();
    }
    if (t == 0) biasf[r] = red[0] + db1[r];
    return;
  }

  // ---------------- GEMM1 path (proven 8-phase schedule, unchanged) ----------------
  const int idx = (lin & 7) * NX + (lin >> 3);
  const int by = idx & 7, bx = idx >> 3;

  const int w = tid >> 6, l = tid & 63;
  const int wm = w >> 2, wn = w & 3;
  const int r15 = l & 15, kq = l >> 4, swr = l & 7;

  const int rl = l >> 3;
  const int scol = ((l & 7) ^ rl) << 4;

  const long ldaB = (long)lda * 2, ldbB = (long)ldb * 2;
  const char* gAs = (const char*)A + ((long)by * 256 + rl) * ldaB + scol;
  const char* gBs = (const char*)B + ((long)bx * 256 + rl) * ldbB + scol;

  auto stA = [&](int buf, int R0, int kt) {
    async16(gAs + (long)R0 * ldaB + (long)kt * 128, (char*)LDS_T(buf, 0) + R0 * 128);
  };
  auto stB = [&](int buf, int R0, int kt) {
    async16(gBs + (long)R0 * ldbB + (long)kt * 128, (char*)LDS_T(buf, 1) + R0 * 128);
  };
  auto stAU0 = [&](int buf, int kt) { stA(buf, w * 8, kt);       stA(buf, 128 + w * 8, kt); };
  auto stAU1 = [&](int buf, int kt) { stA(buf, 64 + w * 8, kt);  stA(buf, 192 + w * 8, kt); };
  auto stBU0 = [&](int buf, int kt) { int R = (w >> 1) * 64 + (w & 1) * 16;      stB(buf, R, kt); stB(buf, R + 8, kt); };
  auto stBU1 = [&](int buf, int kt) { int R = (w >> 1) * 64 + (w & 1) * 16 + 32; stB(buf, R, kt); stB(buf, R + 8, kt); };

  v4f acc[8][4];
#pragma unroll
  for (int m = 0; m < 8; ++m)
#pragma unroll
    for (int n = 0; n < 4; ++n) acc[m][n] = v4f{0.f, 0.f, 0.f, 0.f};
  v8bf a[4][2], b0[2][2], b1[2][2];

  const int NT = K >> 6;
  const int NI = (NT >> 1) - 1;

  stAU0(0, 0); stBU0(0, 0); stBU1(0, 0); stAU1(0, 0);
  stAU0(1, 1); stBU0(1, 1); stBU1(1, 1);
  VM6();
  BAR();

  int kt0 = 0;
  for (int i = 0; i < NI; ++i, kt0 += 2) {
    READ_A(0, 0); READ_B(0, 0, b0);
    stAU1(1, kt0 + 1);
    BAR(); LGKM0(); PRIO1(); MMA(0, 0, b0); PRIO0(); BAR();
    READ_B(0, 1, b1);
    stAU0(0, kt0 + 2);
    BAR(); LGKM0(); PRIO1(); MMA(0, 1, b1); PRIO0(); BAR();
    READ_A(0, 1);
    stBU0(0, kt0 + 2);
    BAR(); LGKM0(); PRIO1(); MMA(1, 1, b1); PRIO0(); BAR();
    stBU1(0, kt0 + 2);
    BAR(); PRIO1(); MMA(1, 0, b0); PRIO0(); VM6(); BAR();
    READ_A(1, 0); READ_B(1, 0, b0);
    stAU1(0, kt0 + 2);
    BAR(); LGKM0(); PRIO1(); MMA(0, 0, b0); PRIO0(); BAR();
    READ_B(1, 1, b1);
    stAU0(1, kt0 + 3);
    BAR(); LGKM0(); PRIO1(); MMA(0, 1, b1); PRIO0(); BAR();
    READ_A(1, 1);
    stBU0(1, kt0 + 3);
    BAR(); LGKM0(); PRIO1(); MMA(1, 1, b1); PRIO0(); BAR();
    stBU1(1, kt0 + 3);
    BAR(); PRIO1(); MMA(1, 0, b0); PRIO0(); VM6(); BAR();
  }

  READ_A(0, 0); READ_B(0, 0, b0);
  stAU1(1, kt0 + 1);
  BAR(); LGKM0(); PRIO1(); MMA(0, 0, b0); PRIO0(); BAR();
  READ_B(0, 1, b1);
  BAR(); LGKM0(); PRIO1(); MMA(0, 1, b1); PRIO0(); BAR();
  READ_A(0, 1);
  BAR(); LGKM0(); PRIO1(); MMA(1, 1, b1); PRIO0(); BAR();
  BAR(); PRIO1(); MMA(1, 0, b0); PRIO0(); VM0(); BAR();
  READ_A(1, 0); READ_B(1, 0, b0);
  BAR(); LGKM0(); PRIO1(); MMA(0, 0, b0); PRIO0(); BAR();
  READ_B(1, 1, b1);
  BAR(); LGKM0(); PRIO1(); MMA(0, 1, b1); PRIO0(); BAR();
  READ_A(1, 1);
  BAR(); LGKM0(); PRIO1(); MMA(1, 1, b1); PRIO0(); BAR();
  PRIO1(); MMA(1, 0, b0); PRIO0();

  const long rowBase = (long)by * 256 + wm * 128 + kq * 4;
  const int colBase = bx * 256 + wn * 64 + r15;
  u16* Ch = (u16*)Cp;
#pragma unroll
  for (int mf = 0; mf < 8; ++mf) {
#pragma unroll
    for (int nf = 0; nf < 4; ++nf) {
      const int col = colBase + nf * 16;
      const float bv = bias ? bias[col] : 0.f;
#pragma unroll
      for (int j = 0; j < 4; ++j) {
        const long row = rowBase + mf * 16 + j;
        float v = acc[mf][nf][j] + bv;
        if (flags & 1) v = fmaxf(v, 0.f);
        Ch[row * ldc + col] = f2bf(v);
      }
    }
  }
}

// ---------------- fused tail: splitK-reduce + gating + dist -> ph -> out ----------------
__global__ __launch_bounds__(256) void k_tail(
    const float* __restrict__ part,  // [S][2048][512] fp32
    const float* __restrict__ biasf, // [512]
    const u16* __restrict__ hg,      // h_all + 12800 (gating cols), row stride 13312
    const float* __restrict__ lw2, const float* __restrict__ lb2,
    const float* __restrict__ bw2, const float* __restrict__ bb2,
    const u16* __restrict__ dw2t,    // [256][512]
    const float* __restrict__ db2,
    const u16* __restrict__ pw1t,    // [256][256]
    const float* __restrict__ pb1,
    const u16* __restrict__ pw2t,    // [256][256]
    const float* __restrict__ pb2,
    float* __restrict__ out, int S) {  // [2048][256] fp32
  __shared__ __align__(16) u16 dhs[16][520];
  __shared__ __align__(16) u16 ds2[16][264];
  __shared__ __align__(16) u16 phs[16][264];
  __shared__ float gl[16];
  const int tid = threadIdx.x;
  const int w = tid >> 6, l = tid & 63;
  const int r = l & 15, kq = l >> 4;
  const int r0 = blockIdx.x * 16;

#pragma unroll
  for (int i = 0; i < 8; ++i) {
    int e = (i * 256 + tid) * 4;
    int row = e >> 9, col = e & 511;
    const float* pp = part + (long)(r0 + row) * 512 + col;
    float4 s = *(const float4*)pp;
    for (int k = 1; k < S; ++k) {
      float4 t = *(const float4*)(pp + (long)k * (2048 * 512));
      s.x += t.x; s.y += t.y; s.z += t.z; s.w += t.w;
    }
    float4 bv = *(const float4*)(biasf + col);
    ushort4 o;
    o.x = f2bf(fmaxf(s.x + bv.x, 0.f));
    o.y = f2bf(fmaxf(s.y + bv.y, 0.f));
    o.z = f2bf(fmaxf(s.z + bv.z, 0.f));
    o.w = f2bf(fmaxf(s.w + bv.w, 0.f));
    *(ushort4*)&dhs[row][col] = o;
  }

#pragma unroll
  for (int j = 0; j < 4; ++j) {
    int rr = w * 4 + j;
    const u16* rowp = hg + (long)(r0 + rr) * 13312;
    float sa = 0.f, sb = 0.f;
#pragma unroll
    for (int jj = 0; jj < 4; ++jj) {
      int i = l * 4 + jj;
      sa += bf2f(rowp[i]) * lw2[i];
      sb += bf2f(rowp[256 + i]) * bw2[i];
    }
#pragma unroll
    for (int off = 32; off > 0; off >>= 1) {
      sa += __shfl_down(sa, off, 64);
      sb += __shfl_down(sb, off, 64);
    }
    if (l == 0) {
      float ga = 1.f / (1.f + expf(-(sa + lb2[0])));
      float gb = 1.f / (1.f + expf(-(sb + bb2[0])));
      gl[rr] = ga * gb;
    }
  }
  __syncthreads();

  v4f acc[4];
#pragma unroll
  for (int n = 0; n < 4; ++n) acc[n] = v4f{0.f, 0.f, 0.f, 0.f};
#pragma unroll 4
  for (int kt = 0; kt < 16; ++kt) {
    v8bf af = *(const v8bf*)&dhs[r][kt * 32 + kq * 8];
#pragma unroll
    for (int n = 0; n < 4; ++n) {
      v8bf bf = *(const v8bf*)(dw2t + (long)(w * 64 + n * 16 + r) * 512 + kt * 32 + kq * 8);
      acc[n] = __builtin_amdgcn_mfma_f32_16x16x32_bf16(af, bf, acc[n], 0, 0, 0);
    }
  }
#pragma unroll
  for (int n = 0; n < 4; ++n) {
    int col = w * 64 + n * 16 + r;
    float bv = db2[col];
#pragma unroll
    for (int j = 0; j < 4; ++j) ds2[kq * 4 + j][col] = f2bf(acc[n][j] + bv);
  }
  __syncthreads();

#pragma unroll
  for (int n = 0; n < 4; ++n) acc[n] = v4f{0.f, 0.f, 0.f, 0.f};
#pragma unroll 4
  for (int kt = 0; kt < 8; ++kt) {
    v8bf af = *(const v8bf*)&ds2[r][kt * 32 + kq * 8];
#pragma unroll
    for (int n = 0; n < 4; ++n) {
      v8bf bf = *(const v8bf*)(pw1t + (long)(w * 64 + n * 16 + r) * 256 + kt * 32 + kq * 8);
      acc[n] = __builtin_amdgcn_mfma_f32_16x16x32_bf16(af, bf, acc[n], 0, 0, 0);
    }
  }
#pragma unroll
  for (int n = 0; n < 4; ++n) {
    int col = w * 64 + n * 16 + r;
    float bv = pb1[col];
#pragma unroll
    for (int j = 0; j < 4; ++j) phs[kq * 4 + j][col] = f2bf(fmaxf(acc[n][j] + bv, 0.f));
  }
  __syncthreads();

#pragma unroll
  for (int n = 0; n < 4; ++n) acc[n] = v4f{0.f, 0.f, 0.f, 0.f};
#pragma unroll 4
  for (int kt = 0; kt < 8; ++kt) {
    v8bf af = *(const v8bf*)&phs[r][kt * 32 + kq * 8];
#pragma unroll
    for (int n = 0; n < 4; ++n) {
      v8bf bf = *(const v8bf*)(pw2t + (long)(w * 64 + n * 16 + r) * 256 + kt * 32 + kq * 8);
      acc[n] = __builtin_amdgcn_mfma_f32_16x16x32_bf16(af, bf, acc[n], 0, 0, 0);
    }
  }
#pragma unroll
  for (int n = 0; n < 4; ++n) {
    int col = w * 64 + n * 16 + r;
    float bv = pb2[col];
#pragma unroll
    for (int j = 0; j < 4; ++j) {
      int row = kq * 4 + j;
      out[(long)(r0 + row) * 256 + col] = (acc[n][j] + bv) * gl[row];
    }
  }
}

extern "C" void kernel_launch(void* const* d_in, const int* in_sizes, int n_in,
                              void* d_out, int out_size, void* d_ws, size_t ws_size,
                              hipStream_t stream) {
  const float* x   = (const float*)d_in[0];
  const float* ew1 = (const float*)d_in[1];
  const float* eb1 = (const float*)d_in[2];
  const float* ew2 = (const float*)d_in[3];
  const float* eb2 = (const float*)d_in[4];
  const float* dw1 = (const float*)d_in[5];
  const float* db1 = (const float*)d_in[6];
  const float* dw2 = (const float*)d_in[7];
  const float* db2 = (const float*)d_in[8];
  const float* lw1 = (const float*)d_in[9];
  const float* lb1 = (const float*)d_in[10];
  const float* lw2 = (const float*)d_in[11];
  const float* lb2 = (const float*)d_in[12];
  const float* bw1 = (const float*)d_in[13];
  const float* bb1 = (const float*)d_in[14];
  const float* bw2 = (const float*)d_in[15];
  const float* bb2 = (const float*)d_in[16];
  const float* pw1 = (const float*)d_in[17];
  const float* pb1 = (const float*)d_in[18];
  const float* pw2 = (const float*)d_in[19];
  const float* pb2 = (const float*)d_in[20];

  // split-K: S=16 -> 1024 blocks = 4/CU (needs 64 MB partials); else proven S=8
  const int S = (ws_size >= (size_t)168 * 1024 * 1024) ? 16 : 8;
  const int Ksplit = 12800 / S;

  char* p = (char*)d_ws;
  auto alloc = [&](size_t bytes) {
    char* q = p;
    p += (bytes + 255) & ~(size_t)255;
    return q;
  };
  u16* xb      = (u16*)alloc((size_t)2048 * 1024 * 2);
  u16* ew1tf   = (u16*)alloc((size_t)13312 * 1024 * 2);  // [ew1t | lw1t | bw1t]
  u16* Wft     = (u16*)alloc((size_t)512 * 12800 * 2);
  u16* dw2t    = (u16*)alloc((size_t)256 * 512 * 2);
  u16* pw1t    = (u16*)alloc((size_t)256 * 256 * 2);
  u16* pw2t    = (u16*)alloc((size_t)256 * 256 * 2);
  float* ebcat = (float*)alloc(13312 * 4);
  float* biasf = (float*)alloc(512 * 4);
  float* part  = (float*)alloc((size_t)S * 2048 * 512 * 4);   // 32 or 64 MB
  u16* h_all   = (u16*)alloc((size_t)2048 * 13312 * 2);
  // ew2b + dw1t live inside `part` (used only before the reduce GEMM writes part)
  u16* ew2b    = (u16*)part;
  u16* dw1t    = (u16*)((char*)part + (((size_t)50 * 256 * 256 * 2 + 255) & ~(size_t)255));
  (void)in_sizes; (void)n_in; (void)out_size;

  // 1. merged precompute
  k_prep<<<dim3(10292), 256, 0, stream>>>(
      x, ew2, ew1, dw1, dw2, lw1, bw1, pw1, pw2, eb1, lb1, bb1,
      xb, ew2b, ew1tf, dw1t, dw2t, pw1t, pw2t, ebcat);

  // 2. combined: GEMM1 (416 blocks) + Wft GEMM (200 pair-blocks) + biasf (256 pair-blocks)
  k_gemm256<<<dim3(872, 1, 1), 512, 0, stream>>>(
      xb, 1024, ew1tf, 1024, h_all, 13312,
      1024, 52, ebcat, 1,
      dw1t, ew2b, Wft, eb2, db1, biasf, 416);

  // 3. reduce GEMM (128^2, split-K, S*64 blocks)
  k_gemm<<<dim3(4, 16, S), 256, 0, stream>>>(
      h_all, 13312, Ksplit, Wft, 12800, Ksplit, part, 512, (long)2048 * 512,
      Ksplit, nullptr, 0, nullptr, 2);

  // 4. fused tail: split-K reduce + gating + dist -> ph -> out (128 blocks x 16 rows)
  k_tail<<<dim3(128), 256, 0, stream>>>(
      part, biasf, h_all + 12800, lw2, lb2, bw2, bb2,
      dw2t, db2, pw1t, pb1, pw2t, pb2, (float*)d_out, S);
}

// Round 13
// 160.499 us; speedup vs baseline: 1.3246x; 1.3246x over previous
//
#include <hip/hip_runtime.h>
#include <hip/hip_bf16.h>

typedef unsigned short u16;
typedef __attribute__((ext_vector_type(8))) __bf16 v8bf;
typedef __attribute__((ext_vector_type(4))) float v4f;

#define DEVINL __device__ __forceinline__

DEVINL u16 f2bf(float f) {
  union { float f; unsigned u; } v; v.f = f;
  unsigned u = v.u;
  return (u16)((u + 0x7FFFu + ((u >> 16) & 1u)) >> 16);  // RNE
}
DEVINL float bf2f(u16 b) {
  union { unsigned u; float f; } v; v.u = ((unsigned)b) << 16;
  return v.f;
}

// async global->LDS, 16B per lane; dest is wave-uniform base + lane*16
DEVINL void async16(const void* g, void* l) {
  __builtin_amdgcn_global_load_lds(
      (__attribute__((address_space(1))) void*)(g),
      (__attribute__((address_space(3))) void*)(l), 16, 0, 0);
}

// ---------------- merged precompute ----------------
DEVINL void f2b_body(const float* __restrict__ src, u16* __restrict__ dst, int base) {
  int i = base + threadIdx.x * 4;
  float4 v = *(const float4*)(src + i);
  unsigned lo = (unsigned)f2bf(v.x) | ((unsigned)f2bf(v.y) << 16);
  unsigned hi = (unsigned)f2bf(v.z) | ((unsigned)f2bf(v.w) << 16);
  uint2 o; o.x = lo; o.y = hi;
  *(uint2*)(dst + i) = o;
}

// 64x64 transpose+convert tile: src fp32 [R][C] -> dst bf16 [C][R]
DEVINL void tr64(u16 (*t)[66], const float* __restrict__ src,
                 u16* __restrict__ dst, int R, int C, int bx, int by) {
  int r0 = by * 64, c0 = bx * 64;
  int tx = threadIdx.x & 15, ty = threadIdx.x >> 4;  // 16x16 threads
#pragma unroll
  for (int i = 0; i < 4; ++i) {
    int rr = ty + i * 16;
    float4 v = *(const float4*)(src + (long)(r0 + rr) * C + c0 + tx * 4);
    u16* d = &t[rr][tx * 4];
    d[0] = f2bf(v.x); d[1] = f2bf(v.y); d[2] = f2bf(v.z); d[3] = f2bf(v.w);
  }
  __syncthreads();
#pragma unroll
  for (int i = 0; i < 4; ++i) {
    int cc = ty + i * 16;
    ushort4 o;
    o.x = t[tx * 4 + 0][cc]; o.y = t[tx * 4 + 1][cc];
    o.z = t[tx * 4 + 2][cc]; o.w = t[tx * 4 + 3][cc];
    *(ushort4*)(dst + (long)(c0 + cc) * R + r0 + tx * 4) = o;
  }
}

__global__ __launch_bounds__(256) void k_prep(
    const float* __restrict__ x, const float* __restrict__ ew2,
    const float* __restrict__ ew1, const float* __restrict__ dw1,
    const float* __restrict__ dw2, const float* __restrict__ lw1,
    const float* __restrict__ bw1, const float* __restrict__ pw1,
    const float* __restrict__ pw2,
    const float* __restrict__ eb1, const float* __restrict__ lb1,
    const float* __restrict__ bb1,
    u16* __restrict__ xb, u16* __restrict__ ew2b, u16* __restrict__ ew1tf,
    u16* __restrict__ dw1t, u16* __restrict__ dw2t,
    u16* __restrict__ pw1t, u16* __restrict__ pw2t,
    float* __restrict__ ebcat) {
  __shared__ u16 tile[64][66];
  int b = blockIdx.x;
  if (b < 2048) { f2b_body(x, xb, b * 1024); return; }
  b -= 2048;
  if (b < 3200) { f2b_body(ew2, ew2b, b * 1024); return; }
  b -= 3200;
  if (b < 3200) {
    int e = b >> 6, t = b & 63;
    tr64(tile, ew1 + (long)e * 1024 * 256, ew1tf + (long)e * 256 * 1024,
         1024, 256, t & 3, t >> 2);
    return;
  }
  b -= 3200;
  if (b < 1600) {
    tr64(tile, dw1, dw1t, 12800, 512, b & 7, b >> 3);
    return;
  }
  b -= 1600;
  if (b < 32) {
    tr64(tile, dw2, dw2t, 512, 256, b & 3, b >> 2);
    return;
  }
  b -= 32;
  if (b < 64) {
    tr64(tile, lw1, ew1tf + (long)12800 * 1024, 1024, 256, b & 3, b >> 2);
    return;
  }
  b -= 64;
  if (b < 64) {
    tr64(tile, bw1, ew1tf + (long)13056 * 1024, 1024, 256, b & 3, b >> 2);
    return;
  }
  b -= 64;
  if (b < 16) {
    tr64(tile, pw1, pw1t, 256, 256, b & 3, b >> 2);
    return;
  }
  b -= 16;
  if (b < 16) {
    tr64(tile, pw2, pw2t, 256, 256, b & 3, b >> 2);
    return;
  }
  b -= 16;
  {
    int i = b * 256 + threadIdx.x;
    float v;
    if (i < 12800) v = eb1[i];
    else if (i < 13056) v = lb1[i - 12800];
    else v = bb1[i - 13056];
    ebcat[i] = v;
  }
}

// ---------------- 128x128 MFMA GEMM body (shared; tid-parameterized, 256 lanes) ----------------
DEVINL void gemm128_body(int tid, u16* __restrict__ sA, u16* __restrict__ sB,
    int bx, int by, int z,
    const u16* __restrict__ A, int lda, long aBatch,
    const u16* __restrict__ B, int ldb, long bBatch,   // B is Bt: [N][K]
    void* __restrict__ Cp, int ldc, long cBatch,
    int K,
    const float* __restrict__ bias, long biasBatch,
    const float* __restrict__ rowscale, int flags) {
  const int w = tid >> 6, l = tid & 63;
  const u16* Ab = A + (long)z * aBatch + (long)by * 128 * lda;
  const u16* Bb = B + (long)z * bBatch + (long)bx * 128 * ldb;
  const int ldaB = lda * 2, ldbB = ldb * 2;
  const int wm = w >> 1, wn = w & 1;
  const int r = l & 15, kq = l >> 4;

  const int f0 = w * 1024 + l * 16;
  const int f1 = f0 + 4096;
  const int row0 = f0 >> 6, cb0 = f0 & 63;
  const int row1 = f1 >> 6, cb1 = f1 & 63;
  const int seg0 = w * 1024, seg1 = seg0 + 4096;

  v4f acc[4][4];
#pragma unroll
  for (int m = 0; m < 4; ++m)
#pragma unroll
    for (int n = 0; n < 4; ++n) acc[m][n] = v4f{0.f, 0.f, 0.f, 0.f};

  const char* gA = (const char*)Ab;
  const char* gB = (const char*)Bb;
  const int nkt = K / 32;

  async16(gA + (long)row0 * ldaB + cb0, (char*)sA + seg0);
  async16(gA + (long)row1 * ldaB + cb1, (char*)sA + seg1);
  async16(gB + (long)row0 * ldbB + cb0, (char*)sB + seg0);
  async16(gB + (long)row1 * ldbB + cb1, (char*)sB + seg1);
  __syncthreads();

  for (int kt = 0; kt < nkt; ++kt) {
    const int cur = kt & 1;
    if (kt + 1 < nkt) {
      const long ko = (long)(kt + 1) * 64;
      async16(gA + ko + (long)row0 * ldaB + cb0, (char*)sA + (cur ^ 1) * 8192 + seg0);
      async16(gA + ko + (long)row1 * ldaB + cb1, (char*)sA + (cur ^ 1) * 8192 + seg1);
      async16(gB + ko + (long)row0 * ldbB + cb0, (char*)sB + (cur ^ 1) * 8192 + seg0);
      async16(gB + ko + (long)row1 * ldbB + cb1, (char*)sB + (cur ^ 1) * 8192 + seg1);
    }
    v8bf af[4], bfr[4];
#pragma unroll
    for (int m = 0; m < 4; ++m)
      af[m] = *(const v8bf*)&sA[cur * 4096 + (wm * 64 + m * 16 + r) * 32 + kq * 8];
#pragma unroll
    for (int n = 0; n < 4; ++n)
      bfr[n] = *(const v8bf*)&sB[cur * 4096 + (wn * 64 + n * 16 + r) * 32 + kq * 8];
#pragma unroll
    for (int m = 0; m < 4; ++m)
#pragma unroll
      for (int n = 0; n < 4; ++n)
        acc[m][n] = __builtin_amdgcn_mfma_f32_16x16x32_bf16(af[m], bfr[n], acc[m][n], 0, 0, 0);
    __syncthreads();
  }

  const float* bz = bias ? (bias + (long)z * biasBatch) : nullptr;
  const long rowBase = (long)by * 128 + wm * 64 + kq * 4;
  const int colBase = bx * 128 + wn * 64 + r;
  float* Cf = (float*)Cp + (long)z * cBatch;
  u16* Ch = (u16*)Cp + (long)z * cBatch;
#pragma unroll
  for (int m = 0; m < 4; ++m) {
#pragma unroll
    for (int n = 0; n < 4; ++n) {
      const int col = colBase + n * 16;
      const float bv = bz ? bz[col] : 0.f;
#pragma unroll
      for (int i = 0; i < 4; ++i) {
        const long row = rowBase + m * 16 + i;
        float v = acc[m][n][i] + bv;
        if (flags & 1) v = fmaxf(v, 0.f);
        if (rowscale) v *= rowscale[row];
        const long idx = row * ldc + col;
        if (flags & 2) Cf[idx] = v;
        else Ch[idx] = f2bf(v);
      }
    }
  }
}

__global__ __launch_bounds__(256) void k_gemm(
    const u16* __restrict__ A, int lda, long aBatch,
    const u16* __restrict__ B, int ldb, long bBatch,
    void* __restrict__ Cp, int ldc, long cBatch,
    int K,
    const float* __restrict__ bias, long biasBatch,
    const float* __restrict__ rowscale, int flags) {
  __shared__ __align__(16) u16 sA[2 * 4096];
  __shared__ __align__(16) u16 sB[2 * 4096];
  gemm128_body(threadIdx.x, sA, sB, blockIdx.x, blockIdx.y, blockIdx.z,
               A, lda, aBatch, B, ldb, bBatch, Cp, ldc, cBatch, K,
               bias, biasBatch, rowscale, flags);
}

// ---- reduce GEMM with z->XCD placement: lin = (y*4+x)*8 + z  (z = lin & 7) ----
// All 64 blocks of one K-slice land on one XCD (round-robin dispatch assumption):
// that slice's B panel (1.6 MB) becomes L2-resident; x-neighbors share A panels.
__global__ __launch_bounds__(256) void k_gemm_red(
    const u16* __restrict__ A, int lda, long aBatch,
    const u16* __restrict__ B, int ldb, long bBatch,
    void* __restrict__ Cp, int ldc, long cBatch,
    int K) {
  __shared__ __align__(16) u16 sA[2 * 4096];
  __shared__ __align__(16) u16 sB[2 * 4096];
  const int lin = blockIdx.x;        // 0..511
  const int z = lin & 7;
  const int xy = lin >> 3;           // 0..63
  const int bx = xy & 3, by = xy >> 2;
  gemm128_body(threadIdx.x, sA, sB, bx, by, z,
               A, lda, aBatch, B, ldb, bBatch, Cp, ldc, cBatch, K,
               nullptr, 0, nullptr, 2);
}

// ======= combined dispatch: 256^2 8-phase GEMM1 blocks + wft/bias filler blocks =======
#define LDS_T(buf, op) (smem + ((buf) * 2 + (op)) * 16384)

#define READ_A(buf, mh) do {                                                   \
  const char* _t = (const char*)LDS_T(buf, 0);                                 \
  _Pragma("unroll") for (int m = 0; m < 4; ++m)                                \
    _Pragma("unroll") for (int kk = 0; kk < 2; ++kk)                           \
      a[m][kk] = *(const v8bf*)(_t +                                           \
        (wm * 128 + (mh) * 64 + m * 16 + r15) * 128 +                          \
        ((kk * 64 + kq * 16) ^ (swr << 4)));                                   \
} while (0)

#define READ_B(buf, nh, br) do {                                               \
  const char* _t = (const char*)LDS_T(buf, 1);                                 \
  _Pragma("unroll") for (int n = 0; n < 2; ++n)                                \
    _Pragma("unroll") for (int kk = 0; kk < 2; ++kk)                           \
      br[n][kk] = *(const v8bf*)(_t +                                          \
        (wn * 64 + (nh) * 32 + n * 16 + r15) * 128 +                          \
        ((kk * 64 + kq * 16) ^ (swr << 4)));                                   \
} while (0)

#define MMA(mh, nh, br) do {                                                   \
  _Pragma("unroll") for (int kk = 0; kk < 2; ++kk)                             \
    _Pragma("unroll") for (int m = 0; m < 4; ++m)                              \
      _Pragma("unroll") for (int n = 0; n < 2; ++n)                            \
        acc[(mh) * 4 + m][(nh) * 2 + n] =                                      \
          __builtin_amdgcn_mfma_f32_16x16x32_bf16(                             \
            a[m][kk], br[n][kk], acc[(mh) * 4 + m][(nh) * 2 + n], 0, 0, 0);    \
} while (0)

#define BAR() __builtin_amdgcn_s_barrier()
#define PRIO1() __builtin_amdgcn_s_setprio(1)
#define PRIO0() __builtin_amdgcn_s_setprio(0)
#define VM6() asm volatile("s_waitcnt vmcnt(6)" ::: "memory")
#define VM0() asm volatile("s_waitcnt vmcnt(0)" ::: "memory")
#define LGKM0() asm volatile("s_waitcnt lgkmcnt(0)" ::: "memory")

__global__ __launch_bounds__(512, 2) void k_gemm256(
    const u16* __restrict__ A, int lda,
    const u16* __restrict__ B, int ldb,
    void* __restrict__ Cp, int ldc,
    int K, int NX,
    const float* __restrict__ bias, int flags,
    const u16* __restrict__ dw1t, const u16* __restrict__ ew2b,
    u16* __restrict__ Wft,
    const float* __restrict__ eb2, const float* __restrict__ db1,
    float* __restrict__ biasf, int ngemm1) {
  __shared__ __align__(16) u16 smem[2 * 2 * 16384];  // 128 KiB

  const int lin = blockIdx.x;
  const int tid = threadIdx.x;

  if (lin >= ngemm1) {
    int fb = lin - ngemm1;
    int sub = tid >> 8, t = tid & 255;
    if (fb < 200) {
      int tt = fb * 2 + sub;
      int bx = tt & 1, by = (tt >> 1) & 3, z = tt >> 3;
      u16* base = smem + sub * 16384;
      gemm128_body(t, base, base + 8192, bx, by, z,
                   dw1t, 12800, 256, ew2b, 256, (long)256 * 256,
                   Wft, 12800, 256, 256, nullptr, 0, nullptr, 0);
      return;
    }
    int r = (fb - 200) * 2 + sub;
    const u16* row = dw1t + (long)r * 12800;
    float s = 0.f;
    for (int c = t; c < 1600; c += 256) {
      ushort4 a0 = *(const ushort4*)(row + c * 8);
      ushort4 a1 = *(const ushort4*)(row + c * 8 + 4);
      float4 e0 = *(const float4*)(eb2 + c * 8);
      float4 e1 = *(const float4*)(eb2 + c * 8 + 4);
      s += bf2f(a0.x) * e0.x + bf2f(a0.y) * e0.y + bf2f(a0.z) * e0.z + bf2f(a0.w) * e0.w
         + bf2f(a1.x) * e1.x + bf2f(a1.y) * e1.y + bf2f(a1.z) * e1.z + bf2f(a1.w) * e1.w;
    }
    float* red = (float*)smem + sub * 256;
    red[t] = s;
    __syncthreads();
    for (int off = 128; off > 0; off >>= 1) {
      if (t < off) red[t] += red[t + off];
      __syncthreads();
    }
    if (t == 0) biasf[r] = red[0] + db1[r];
    return;
  }

  // ---------------- GEMM1 path (proven 8-phase schedule, unchanged) ----------------
  const int idx = (lin & 7) * NX + (lin >> 3);
  const int by = idx & 7, bx = idx >> 3;

  const int w = tid >> 6, l = tid & 63;
  const int wm = w >> 2, wn = w & 3;
  const int r15 = l & 15, kq = l >> 4, swr = l & 7;

  const int rl = l >> 3;
  const int scol = ((l & 7) ^ rl) << 4;

  const long ldaB = (long)lda * 2, ldbB = (long)ldb * 2;
  const char* gAs = (const char*)A + ((long)by * 256 + rl) * ldaB + scol;
  const char* gBs = (const char*)B + ((long)bx * 256 + rl) * ldbB + scol;

  auto stA = [&](int buf, int R0, int kt) {
    async16(gAs + (long)R0 * ldaB + (long)kt * 128, (char*)LDS_T(buf, 0) + R0 * 128);
  };
  auto stB = [&](int buf, int R0, int kt) {
    async16(gBs + (long)R0 * ldbB + (long)kt * 128, (char*)LDS_T(buf, 1) + R0 * 128);
  };
  auto stAU0 = [&](int buf, int kt) { stA(buf, w * 8, kt);       stA(buf, 128 + w * 8, kt); };
  auto stAU1 = [&](int buf, int kt) { stA(buf, 64 + w * 8, kt);  stA(buf, 192 + w * 8, kt); };
  auto stBU0 = [&](int buf, int kt) { int R = (w >> 1) * 64 + (w & 1) * 16;      stB(buf, R, kt); stB(buf, R + 8, kt); };
  auto stBU1 = [&](int buf, int kt) { int R = (w >> 1) * 64 + (w & 1) * 16 + 32; stB(buf, R, kt); stB(buf, R + 8, kt); };

  v4f acc[8][4];
#pragma unroll
  for (int m = 0; m < 8; ++m)
#pragma unroll
    for (int n = 0; n < 4; ++n) acc[m][n] = v4f{0.f, 0.f, 0.f, 0.f};
  v8bf a[4][2], b0[2][2], b1[2][2];

  const int NT = K >> 6;
  const int NI = (NT >> 1) - 1;

  stAU0(0, 0); stBU0(0, 0); stBU1(0, 0); stAU1(0, 0);
  stAU0(1, 1); stBU0(1, 1); stBU1(1, 1);
  VM6();
  BAR();

  int kt0 = 0;
  for (int i = 0; i < NI; ++i, kt0 += 2) {
    READ_A(0, 0); READ_B(0, 0, b0);
    stAU1(1, kt0 + 1);
    BAR(); LGKM0(); PRIO1(); MMA(0, 0, b0); PRIO0(); BAR();
    READ_B(0, 1, b1);
    stAU0(0, kt0 + 2);
    BAR(); LGKM0(); PRIO1(); MMA(0, 1, b1); PRIO0(); BAR();
    READ_A(0, 1);
    stBU0(0, kt0 + 2);
    BAR(); LGKM0(); PRIO1(); MMA(1, 1, b1); PRIO0(); BAR();
    stBU1(0, kt0 + 2);
    BAR(); PRIO1(); MMA(1, 0, b0); PRIO0(); VM6(); BAR();
    READ_A(1, 0); READ_B(1, 0, b0);
    stAU1(0, kt0 + 2);
    BAR(); LGKM0(); PRIO1(); MMA(0, 0, b0); PRIO0(); BAR();
    READ_B(1, 1, b1);
    stAU0(1, kt0 + 3);
    BAR(); LGKM0(); PRIO1(); MMA(0, 1, b1); PRIO0(); BAR();
    READ_A(1, 1);
    stBU0(1, kt0 + 3);
    BAR(); LGKM0(); PRIO1(); MMA(1, 1, b1); PRIO0(); BAR();
    stBU1(1, kt0 + 3);
    BAR(); PRIO1(); MMA(1, 0, b0); PRIO0(); VM6(); BAR();
  }

  READ_A(0, 0); READ_B(0, 0, b0);
  stAU1(1, kt0 + 1);
  BAR(); LGKM0(); PRIO1(); MMA(0, 0, b0); PRIO0(); BAR();
  READ_B(0, 1, b1);
  BAR(); LGKM0(); PRIO1(); MMA(0, 1, b1); PRIO0(); BAR();
  READ_A(0, 1);
  BAR(); LGKM0(); PRIO1(); MMA(1, 1, b1); PRIO0(); BAR();
  BAR(); PRIO1(); MMA(1, 0, b0); PRIO0(); VM0(); BAR();
  READ_A(1, 0); READ_B(1, 0, b0);
  BAR(); LGKM0(); PRIO1(); MMA(0, 0, b0); PRIO0(); BAR();
  READ_B(1, 1, b1);
  BAR(); LGKM0(); PRIO1(); MMA(0, 1, b1); PRIO0(); BAR();
  READ_A(1, 1);
  BAR(); LGKM0(); PRIO1(); MMA(1, 1, b1); PRIO0(); BAR();
  PRIO1(); MMA(1, 0, b0); PRIO0();

  const long rowBase = (long)by * 256 + wm * 128 + kq * 4;
  const int colBase = bx * 256 + wn * 64 + r15;
  u16* Ch = (u16*)Cp;
#pragma unroll
  for (int mf = 0; mf < 8; ++mf) {
#pragma unroll
    for (int nf = 0; nf < 4; ++nf) {
      const int col = colBase + nf * 16;
      const float bv = bias ? bias[col] : 0.f;
#pragma unroll
      for (int j = 0; j < 4; ++j) {
        const long row = rowBase + mf * 16 + j;
        float v = acc[mf][nf][j] + bv;
        if (flags & 1) v = fmaxf(v, 0.f);
        Ch[row * ldc + col] = f2bf(v);
      }
    }
  }
}

// ---------------- fused tail: splitK-reduce + gating + dist -> ph -> out ----------------
__global__ __launch_bounds__(256) void k_tail(
    const float* __restrict__ part,  // [8][2048][512] fp32
    const float* __restrict__ biasf, // [512]
    const u16* __restrict__ hg,      // h_all + 12800 (gating cols), row stride 13312
    const float* __restrict__ lw2, const float* __restrict__ lb2,
    const float* __restrict__ bw2, const float* __restrict__ bb2,
    const u16* __restrict__ dw2t,    // [256][512]
    const float* __restrict__ db2,
    const u16* __restrict__ pw1t,    // [256][256]
    const float* __restrict__ pb1,
    const u16* __restrict__ pw2t,    // [256][256]
    const float* __restrict__ pb2,
    float* __restrict__ out) {       // [2048][256] fp32
  __shared__ __align__(16) u16 dhs[16][520];
  __shared__ __align__(16) u16 ds2[16][264];
  __shared__ __align__(16) u16 phs[16][264];
  __shared__ float gl[16];
  const int tid = threadIdx.x;
  const int w = tid >> 6, l = tid & 63;
  const int r = l & 15, kq = l >> 4;
  const int r0 = blockIdx.x * 16;

#pragma unroll
  for (int i = 0; i < 8; ++i) {
    int e = (i * 256 + tid) * 4;
    int row = e >> 9, col = e & 511;
    const float* pp = part + (long)(r0 + row) * 512 + col;
    float4 s = *(const float4*)pp;
#pragma unroll
    for (int k = 1; k < 8; ++k) {
      float4 t = *(const float4*)(pp + (long)k * (2048 * 512));
      s.x += t.x; s.y += t.y; s.z += t.z; s.w += t.w;
    }
    float4 bv = *(const float4*)(biasf + col);
    ushort4 o;
    o.x = f2bf(fmaxf(s.x + bv.x, 0.f));
    o.y = f2bf(fmaxf(s.y + bv.y, 0.f));
    o.z = f2bf(fmaxf(s.z + bv.z, 0.f));
    o.w = f2bf(fmaxf(s.w + bv.w, 0.f));
    *(ushort4*)&dhs[row][col] = o;
  }

#pragma unroll
  for (int j = 0; j < 4; ++j) {
    int rr = w * 4 + j;
    const u16* rowp = hg + (long)(r0 + rr) * 13312;
    float sa = 0.f, sb = 0.f;
#pragma unroll
    for (int jj = 0; jj < 4; ++jj) {
      int i = l * 4 + jj;
      sa += bf2f(rowp[i]) * lw2[i];
      sb += bf2f(rowp[256 + i]) * bw2[i];
    }
#pragma unroll
    for (int off = 32; off > 0; off >>= 1) {
      sa += __shfl_down(sa, off, 64);
      sb += __shfl_down(sb, off, 64);
    }
    if (l == 0) {
      float ga = 1.f / (1.f + expf(-(sa + lb2[0])));
      float gb = 1.f / (1.f + expf(-(sb + bb2[0])));
      gl[rr] = ga * gb;
    }
  }
  __syncthreads();

  v4f acc[4];
#pragma unroll
  for (int n = 0; n < 4; ++n) acc[n] = v4f{0.f, 0.f, 0.f, 0.f};
#pragma unroll 4
  for (int kt = 0; kt < 16; ++kt) {
    v8bf af = *(const v8bf*)&dhs[r][kt * 32 + kq * 8];
#pragma unroll
    for (int n = 0; n < 4; ++n) {
      v8bf bf = *(const v8bf*)(dw2t + (long)(w * 64 + n * 16 + r) * 512 + kt * 32 + kq * 8);
      acc[n] = __builtin_amdgcn_mfma_f32_16x16x32_bf16(af, bf, acc[n], 0, 0, 0);
    }
  }
#pragma unroll
  for (int n = 0; n < 4; ++n) {
    int col = w * 64 + n * 16 + r;
    float bv = db2[col];
#pragma unroll
    for (int j = 0; j < 4; ++j) ds2[kq * 4 + j][col] = f2bf(acc[n][j] + bv);
  }
  __syncthreads();

#pragma unroll
  for (int n = 0; n < 4; ++n) acc[n] = v4f{0.f, 0.f, 0.f, 0.f};
#pragma unroll 4
  for (int kt = 0; kt < 8; ++kt) {
    v8bf af = *(const v8bf*)&ds2[r][kt * 32 + kq * 8];
#pragma unroll
    for (int n = 0; n < 4; ++n) {
      v8bf bf = *(const v8bf*)(pw1t + (long)(w * 64 + n * 16 + r) * 256 + kt * 32 + kq * 8);
      acc[n] = __builtin_amdgcn_mfma_f32_16x16x32_bf16(af, bf, acc[n], 0, 0, 0);
    }
  }
#pragma unroll
  for (int n = 0; n < 4; ++n) {
    int col = w * 64 + n * 16 + r;
    float bv = pb1[col];
#pragma unroll
    for (int j = 0; j < 4; ++j) phs[kq * 4 + j][col] = f2bf(fmaxf(acc[n][j] + bv, 0.f));
  }
  __syncthreads();

#pragma unroll
  for (int n = 0; n < 4; ++n) acc[n] = v4f{0.f, 0.f, 0.f, 0.f};
#pragma unroll 4
  for (int kt = 0; kt < 8; ++kt) {
    v8bf af = *(const v8bf*)&phs[r][kt * 32 + kq * 8];
#pragma unroll
    for (int n = 0; n < 4; ++n) {
      v8bf bf = *(const v8bf*)(pw2t + (long)(w * 64 + n * 16 + r) * 256 + kt * 32 + kq * 8);
      acc[n] = __builtin_amdgcn_mfma_f32_16x16x32_bf16(af, bf, acc[n], 0, 0, 0);
    }
  }
#pragma unroll
  for (int n = 0; n < 4; ++n) {
    int col = w * 64 + n * 16 + r;
    float bv = pb2[col];
#pragma unroll
    for (int j = 0; j < 4; ++j) {
      int row = kq * 4 + j;
      out[(long)(r0 + row) * 256 + col] = (acc[n][j] + bv) * gl[row];
    }
  }
}

extern "C" void kernel_launch(void* const* d_in, const int* in_sizes, int n_in,
                              void* d_out, int out_size, void* d_ws, size_t ws_size,
                              hipStream_t stream) {
  const float* x   = (const float*)d_in[0];
  const float* ew1 = (const float*)d_in[1];
  const float* eb1 = (const float*)d_in[2];
  const float* ew2 = (const float*)d_in[3];
  const float* eb2 = (const float*)d_in[4];
  const float* dw1 = (const float*)d_in[5];
  const float* db1 = (const float*)d_in[6];
  const float* dw2 = (const float*)d_in[7];
  const float* db2 = (const float*)d_in[8];
  const float* lw1 = (const float*)d_in[9];
  const float* lb1 = (const float*)d_in[10];
  const float* lw2 = (const float*)d_in[11];
  const float* lb2 = (const float*)d_in[12];
  const float* bw1 = (const float*)d_in[13];
  const float* bb1 = (const float*)d_in[14];
  const float* bw2 = (const float*)d_in[15];
  const float* bb2 = (const float*)d_in[16];
  const float* pw1 = (const float*)d_in[17];
  const float* pb1 = (const float*)d_in[18];
  const float* pw2 = (const float*)d_in[19];
  const float* pb2 = (const float*)d_in[20];

  const int S = 8, Ksplit = 1600;  // proven config (R9): 512 blocks = 2/CU, 32 MB partials

  char* p = (char*)d_ws;
  auto alloc = [&](size_t bytes) {
    char* q = p;
    p += (bytes + 255) & ~(size_t)255;
    return q;
  };
  u16* xb      = (u16*)alloc((size_t)2048 * 1024 * 2);
  u16* ew1tf   = (u16*)alloc((size_t)13312 * 1024 * 2);  // [ew1t | lw1t | bw1t]
  u16* Wft     = (u16*)alloc((size_t)512 * 12800 * 2);
  u16* dw2t    = (u16*)alloc((size_t)256 * 512 * 2);
  u16* pw1t    = (u16*)alloc((size_t)256 * 256 * 2);
  u16* pw2t    = (u16*)alloc((size_t)256 * 256 * 2);
  float* ebcat = (float*)alloc(13312 * 4);
  float* biasf = (float*)alloc(512 * 4);
  float* part  = (float*)alloc((size_t)S * 2048 * 512 * 4);   // 32 MB
  u16* h_all   = (u16*)alloc((size_t)2048 * 13312 * 2);
  // ew2b + dw1t live inside `part` (used only before the reduce GEMM writes part)
  u16* ew2b    = (u16*)part;
  u16* dw1t    = (u16*)((char*)part + (((size_t)50 * 256 * 256 * 2 + 255) & ~(size_t)255));
  (void)in_sizes; (void)n_in; (void)out_size; (void)ws_size;

  // 1. merged precompute
  k_prep<<<dim3(10292), 256, 0, stream>>>(
      x, ew2, ew1, dw1, dw2, lw1, bw1, pw1, pw2, eb1, lb1, bb1,
      xb, ew2b, ew1tf, dw1t, dw2t, pw1t, pw2t, ebcat);

  // 2. combined: GEMM1 (416 blocks) + Wft GEMM (200 pair-blocks) + biasf (256 pair-blocks)
  k_gemm256<<<dim3(872, 1, 1), 512, 0, stream>>>(
      xb, 1024, ew1tf, 1024, h_all, 13312,
      1024, 52, ebcat, 1,
      dw1t, ew2b, Wft, eb2, db1, biasf, 416);

  // 3. reduce GEMM (128^2, split-K S=8, z->XCD placement)
  k_gemm_red<<<dim3(512), 256, 0, stream>>>(
      h_all, 13312, Ksplit, Wft, 12800, Ksplit, part, 512, (long)2048 * 512,
      Ksplit);

  // 4. fused tail: split-K reduce + gating + dist -> ph -> out (128 blocks x 16 rows)
  k_tail<<<dim3(128), 256, 0, stream>>>(
      part, biasf, h_all + 12800, lw2, lb2, bw2, bb2,
      dw2t, db2, pw1t, pb1, pw2t, pb2, (float*)d_out);
}

// Round 14
// 159.908 us; speedup vs baseline: 1.3295x; 1.0037x over previous
//
#include <hip/hip_runtime.h>
#include <hip/hip_bf16.h>

typedef unsigned short u16;
typedef __attribute__((ext_vector_type(8))) __bf16 v8bf;
typedef __attribute__((ext_vector_type(4))) float v4f;

#define DEVINL __device__ __forceinline__

DEVINL u16 f2bf(float f) {
  union { float f; unsigned u; } v; v.f = f;
  unsigned u = v.u;
  return (u16)((u + 0x7FFFu + ((u >> 16) & 1u)) >> 16);  // RNE
}
DEVINL float bf2f(u16 b) {
  union { unsigned u; float f; } v; v.u = ((unsigned)b) << 16;
  return v.f;
}

// async global->LDS, 16B per lane; dest is wave-uniform base + lane*16
DEVINL void async16(const void* g, void* l) {
  __builtin_amdgcn_global_load_lds(
      (__attribute__((address_space(1))) void*)(g),
      (__attribute__((address_space(3))) void*)(l), 16, 0, 0);
}

// ---------------- merged precompute ----------------
DEVINL void f2b_body(const float* __restrict__ src, u16* __restrict__ dst, int base) {
  int i = base + threadIdx.x * 4;
  float4 v = *(const float4*)(src + i);
  unsigned lo = (unsigned)f2bf(v.x) | ((unsigned)f2bf(v.y) << 16);
  unsigned hi = (unsigned)f2bf(v.z) | ((unsigned)f2bf(v.w) << 16);
  uint2 o; o.x = lo; o.y = hi;
  *(uint2*)(dst + i) = o;
}

// 64x64 transpose+convert tile: src fp32 [R][C] -> dst bf16 [C][R]
DEVINL void tr64(u16 (*t)[66], const float* __restrict__ src,
                 u16* __restrict__ dst, int R, int C, int bx, int by) {
  int r0 = by * 64, c0 = bx * 64;
  int tx = threadIdx.x & 15, ty = threadIdx.x >> 4;  // 16x16 threads
#pragma unroll
  for (int i = 0; i < 4; ++i) {
    int rr = ty + i * 16;
    float4 v = *(const float4*)(src + (long)(r0 + rr) * C + c0 + tx * 4);
    u16* d = &t[rr][tx * 4];
    d[0] = f2bf(v.x); d[1] = f2bf(v.y); d[2] = f2bf(v.z); d[3] = f2bf(v.w);
  }
  __syncthreads();
#pragma unroll
  for (int i = 0; i < 4; ++i) {
    int cc = ty + i * 16;
    ushort4 o;
    o.x = t[tx * 4 + 0][cc]; o.y = t[tx * 4 + 1][cc];
    o.z = t[tx * 4 + 2][cc]; o.w = t[tx * 4 + 3][cc];
    *(ushort4*)(dst + (long)(c0 + cc) * R + r0 + tx * 4) = o;
  }
}

__global__ __launch_bounds__(256) void k_prep(
    const float* __restrict__ x, const float* __restrict__ ew2,
    const float* __restrict__ ew1, const float* __restrict__ dw1,
    const float* __restrict__ dw2, const float* __restrict__ lw1,
    const float* __restrict__ bw1, const float* __restrict__ pw1,
    const float* __restrict__ pw2,
    const float* __restrict__ eb1, const float* __restrict__ lb1,
    const float* __restrict__ bb1,
    u16* __restrict__ xb, u16* __restrict__ ew2b, u16* __restrict__ ew1tf,
    u16* __restrict__ dw1t, u16* __restrict__ dw2t,
    u16* __restrict__ pw1t, u16* __restrict__ pw2t,
    float* __restrict__ ebcat) {
  __shared__ u16 tile[64][66];
  int b = blockIdx.x;
  if (b < 2048) { f2b_body(x, xb, b * 1024); return; }
  b -= 2048;
  if (b < 3200) { f2b_body(ew2, ew2b, b * 1024); return; }
  b -= 3200;
  if (b < 3200) {
    int e = b >> 6, t = b & 63;
    tr64(tile, ew1 + (long)e * 1024 * 256, ew1tf + (long)e * 256 * 1024,
         1024, 256, t & 3, t >> 2);
    return;
  }
  b -= 3200;
  if (b < 1600) {
    tr64(tile, dw1, dw1t, 12800, 512, b & 7, b >> 3);
    return;
  }
  b -= 1600;
  if (b < 32) {
    tr64(tile, dw2, dw2t, 512, 256, b & 3, b >> 2);
    return;
  }
  b -= 32;
  if (b < 64) {
    tr64(tile, lw1, ew1tf + (long)12800 * 1024, 1024, 256, b & 3, b >> 2);
    return;
  }
  b -= 64;
  if (b < 64) {
    tr64(tile, bw1, ew1tf + (long)13056 * 1024, 1024, 256, b & 3, b >> 2);
    return;
  }
  b -= 64;
  if (b < 16) {
    tr64(tile, pw1, pw1t, 256, 256, b & 3, b >> 2);
    return;
  }
  b -= 16;
  if (b < 16) {
    tr64(tile, pw2, pw2t, 256, 256, b & 3, b >> 2);
    return;
  }
  b -= 16;
  {
    int i = b * 256 + threadIdx.x;
    float v;
    if (i < 12800) v = eb1[i];
    else if (i < 13056) v = lb1[i - 12800];
    else v = bb1[i - 13056];
    ebcat[i] = v;
  }
}

// ------- 128x128 MFMA GEMM body, compile-time strides (256 lanes, tid-param) -------
template<int LDA, int LDB, int LDC, int K, bool OUTF32>
DEVINL void gemm128_t(int tid, u16* __restrict__ sA, u16* __restrict__ sB,
    int bx, int by, int z,
    const u16* __restrict__ A, long aBatch,
    const u16* __restrict__ B, long bBatch,   // B is Bt: [N][K]
    void* __restrict__ Cp, long cBatch) {
  const int w = tid >> 6, l = tid & 63;
  const u16* Ab = A + z * aBatch + (long)by * 128 * LDA;
  const u16* Bb = B + z * bBatch + (long)bx * 128 * LDB;
  constexpr int ldaB = LDA * 2, ldbB = LDB * 2;
  constexpr int nkt = K / 32;
  const int wm = w >> 1, wn = w & 1;
  const int r = l & 15, kq = l >> 4;

  const int f0 = w * 1024 + l * 16;
  const int f1 = f0 + 4096;
  const int row0 = f0 >> 6, cb0 = f0 & 63;
  const int row1 = f1 >> 6, cb1 = f1 & 63;
  const int seg0 = w * 1024, seg1 = seg0 + 4096;

  v4f acc[4][4];
#pragma unroll
  for (int m = 0; m < 4; ++m)
#pragma unroll
    for (int n = 0; n < 4; ++n) acc[m][n] = v4f{0.f, 0.f, 0.f, 0.f};

  const char* gA = (const char*)Ab;
  const char* gB = (const char*)Bb;

  async16(gA + (long)row0 * ldaB + cb0, (char*)sA + seg0);
  async16(gA + (long)row1 * ldaB + cb1, (char*)sA + seg1);
  async16(gB + (long)row0 * ldbB + cb0, (char*)sB + seg0);
  async16(gB + (long)row1 * ldbB + cb1, (char*)sB + seg1);
  __syncthreads();

  for (int kt = 0; kt < nkt; ++kt) {
    const int cur = kt & 1;
    if (kt + 1 < nkt) {
      const long ko = (long)(kt + 1) * 64;
      async16(gA + ko + (long)row0 * ldaB + cb0, (char*)sA + (cur ^ 1) * 8192 + seg0);
      async16(gA + ko + (long)row1 * ldaB + cb1, (char*)sA + (cur ^ 1) * 8192 + seg1);
      async16(gB + ko + (long)row0 * ldbB + cb0, (char*)sB + (cur ^ 1) * 8192 + seg0);
      async16(gB + ko + (long)row1 * ldbB + cb1, (char*)sB + (cur ^ 1) * 8192 + seg1);
    }
    v8bf af[4], bfr[4];
#pragma unroll
    for (int m = 0; m < 4; ++m)
      af[m] = *(const v8bf*)&sA[cur * 4096 + (wm * 64 + m * 16 + r) * 32 + kq * 8];
#pragma unroll
    for (int n = 0; n < 4; ++n)
      bfr[n] = *(const v8bf*)&sB[cur * 4096 + (wn * 64 + n * 16 + r) * 32 + kq * 8];
#pragma unroll
    for (int m = 0; m < 4; ++m)
#pragma unroll
      for (int n = 0; n < 4; ++n)
        acc[m][n] = __builtin_amdgcn_mfma_f32_16x16x32_bf16(af[m], bfr[n], acc[m][n], 0, 0, 0);
    __syncthreads();
  }

  const long rowBase = (long)by * 128 + wm * 64 + kq * 4;
  const int colBase = bx * 128 + wn * 64 + r;
  float* Cf = (float*)Cp + z * cBatch;
  u16* Ch = (u16*)Cp + z * cBatch;
#pragma unroll
  for (int m = 0; m < 4; ++m) {
#pragma unroll
    for (int n = 0; n < 4; ++n) {
      const int col = colBase + n * 16;
#pragma unroll
      for (int i = 0; i < 4; ++i) {
        const long row = rowBase + m * 16 + i;
        float v = acc[m][n][i];
        const long idx = row * LDC + col;
        if (OUTF32) Cf[idx] = v;
        else Ch[idx] = f2bf(v);
      }
    }
  }
}

// ---- reduce GEMM with z->XCD placement: z = lin & 7 (round-robin dispatch) ----
// All 64 blocks of one K-slice land on one XCD: that slice's B panel (1.6 MB)
// becomes L2-resident; x-neighbors share A panels. [verified R13: -9.3 us]
__global__ __launch_bounds__(256) void k_gemm_red(
    const u16* __restrict__ A, const u16* __restrict__ B,
    float* __restrict__ Cp) {
  __shared__ __align__(16) u16 sA[2 * 4096];
  __shared__ __align__(16) u16 sB[2 * 4096];
  const int lin = blockIdx.x;        // 0..511
  const int z = lin & 7;
  const int xy = lin >> 3;           // 0..63
  const int bx = xy & 3, by = xy >> 2;
  gemm128_t<13312, 12800, 512, 1600, true>(
      threadIdx.x, sA, sB, bx, by, z,
      A, 1600, B, 1600, Cp, (long)2048 * 512);
}

// ======= combined dispatch: 256^2 8-phase GEMM1 blocks + wft/bias filler blocks =======
// GEMM1 constants: lda=ldb=1024, ldc=13312, K=1024, NX=52, relu, bf16 out.
#define LDS_T(buf, op) (smem + ((buf) * 2 + (op)) * 16384)

#define READ_A(buf, mh) do {                                                   \
  const char* _t = (const char*)LDS_T(buf, 0);                                 \
  _Pragma("unroll") for (int m = 0; m < 4; ++m)                                \
    _Pragma("unroll") for (int kk = 0; kk < 2; ++kk)                           \
      a[m][kk] = *(const v8bf*)(_t +                                           \
        (wm * 128 + (mh) * 64 + m * 16 + r15) * 128 +                          \
        ((kk * 64 + kq * 16) ^ (swr << 4)));                                   \
} while (0)

#define READ_B(buf, nh, br) do {                                               \
  const char* _t = (const char*)LDS_T(buf, 1);                                 \
  _Pragma("unroll") for (int n = 0; n < 2; ++n)                                \
    _Pragma("unroll") for (int kk = 0; kk < 2; ++kk)                           \
      br[n][kk] = *(const v8bf*)(_t +                                          \
        (wn * 64 + (nh) * 32 + n * 16 + r15) * 128 +                          \
        ((kk * 64 + kq * 16) ^ (swr << 4)));                                   \
} while (0)

#define MMA(mh, nh, br) do {                                                   \
  _Pragma("unroll") for (int kk = 0; kk < 2; ++kk)                             \
    _Pragma("unroll") for (int m = 0; m < 4; ++m)                              \
      _Pragma("unroll") for (int n = 0; n < 2; ++n)                            \
        acc[(mh) * 4 + m][(nh) * 2 + n] =                                      \
          __builtin_amdgcn_mfma_f32_16x16x32_bf16(                             \
            a[m][kk], br[n][kk], acc[(mh) * 4 + m][(nh) * 2 + n], 0, 0, 0);    \
} while (0)

#define BAR() __builtin_amdgcn_s_barrier()
#define PRIO1() __builtin_amdgcn_s_setprio(1)
#define PRIO0() __builtin_amdgcn_s_setprio(0)
#define VM6() asm volatile("s_waitcnt vmcnt(6)" ::: "memory")
#define VM0() asm volatile("s_waitcnt vmcnt(0)" ::: "memory")
#define LGKM0() asm volatile("s_waitcnt lgkmcnt(0)" ::: "memory")

__global__ __launch_bounds__(512, 2) void k_gemm256(
    const u16* __restrict__ A,       // xb [2048][1024]
    const u16* __restrict__ B,       // ew1tf [13312][1024]
    u16* __restrict__ Cp,            // h_all, ldc=13312
    const float* __restrict__ bias,  // ebcat
    const u16* __restrict__ dw1t, const u16* __restrict__ ew2b,
    u16* __restrict__ Wft,
    const float* __restrict__ eb2, const float* __restrict__ db1,
    float* __restrict__ biasf) {
  __shared__ __align__(16) u16 smem[2 * 2 * 16384];  // 128 KiB
  constexpr int NGEMM1 = 416, NX = 52, K = 1024, LDAB = 2048, LDC = 13312;

  const int lin = blockIdx.x;
  const int tid = threadIdx.x;

  if (lin >= NGEMM1) {
    int fb = lin - NGEMM1;
    int sub = tid >> 8, t = tid & 255;
    if (fb < 200) {
      int tt = fb * 2 + sub;
      int bx = tt & 1, by = (tt >> 1) & 3, z = tt >> 3;
      u16* base = smem + sub * 16384;
      gemm128_t<12800, 256, 12800, 256, false>(
          t, base, base + 8192, bx, by, z,
          dw1t, 256, ew2b, (long)256 * 256, Wft, 256);
      return;
    }
    int r = (fb - 200) * 2 + sub;
    const u16* row = dw1t + (long)r * 12800;
    float s = 0.f;
    for (int c = t; c < 1600; c += 256) {
      ushort4 a0 = *(const ushort4*)(row + c * 8);
      ushort4 a1 = *(const ushort4*)(row + c * 8 + 4);
      float4 e0 = *(const float4*)(eb2 + c * 8);
      float4 e1 = *(const float4*)(eb2 + c * 8 + 4);
      s += bf2f(a0.x) * e0.x + bf2f(a0.y) * e0.y + bf2f(a0.z) * e0.z + bf2f(a0.w) * e0.w
         + bf2f(a1.x) * e1.x + bf2f(a1.y) * e1.y + bf2f(a1.z) * e1.z + bf2f(a1.w) * e1.w;
    }
    float* red = (float*)smem + sub * 256;
    red[t] = s;
    __syncthreads();
    for (int off = 128; off > 0; off >>= 1) {
      if (t < off) red[t] += red[t + off];
      __syncthreads();
    }
    if (t == 0) biasf[r] = red[0] + db1[r];
    return;
  }

  // ---------------- GEMM1 path (proven 8-phase schedule, constants folded) ----------------
  const int idx = (lin & 7) * NX + (lin >> 3);
  const int by = idx & 7, bx = idx >> 3;

  const int w = tid >> 6, l = tid & 63;
  const int wm = w >> 2, wn = w & 3;
  const int r15 = l & 15, kq = l >> 4, swr = l & 7;

  const int rl = l >> 3;
  const int scol = ((l & 7) ^ rl) << 4;

  const char* gAs = (const char*)A + ((long)by * 256 + rl) * LDAB + scol;
  const char* gBs = (const char*)B + ((long)bx * 256 + rl) * LDAB + scol;

  auto stA = [&](int buf, int R0, int kt) {
    async16(gAs + (long)R0 * LDAB + (long)kt * 128, (char*)LDS_T(buf, 0) + R0 * 128);
  };
  auto stB = [&](int buf, int R0, int kt) {
    async16(gBs + (long)R0 * LDAB + (long)kt * 128, (char*)LDS_T(buf, 1) + R0 * 128);
  };
  auto stAU0 = [&](int buf, int kt) { stA(buf, w * 8, kt);       stA(buf, 128 + w * 8, kt); };
  auto stAU1 = [&](int buf, int kt) { stA(buf, 64 + w * 8, kt);  stA(buf, 192 + w * 8, kt); };
  auto stBU0 = [&](int buf, int kt) { int R = (w >> 1) * 64 + (w & 1) * 16;      stB(buf, R, kt); stB(buf, R + 8, kt); };
  auto stBU1 = [&](int buf, int kt) { int R = (w >> 1) * 64 + (w & 1) * 16 + 32; stB(buf, R, kt); stB(buf, R + 8, kt); };

  v4f acc[8][4];
#pragma unroll
  for (int m = 0; m < 8; ++m)
#pragma unroll
    for (int n = 0; n < 4; ++n) acc[m][n] = v4f{0.f, 0.f, 0.f, 0.f};
  v8bf a[4][2], b0[2][2], b1[2][2];

  constexpr int NT = K >> 6;        // 16
  constexpr int NI = (NT >> 1) - 1; // 7

  stAU0(0, 0); stBU0(0, 0); stBU1(0, 0); stAU1(0, 0);
  stAU0(1, 1); stBU0(1, 1); stBU1(1, 1);
  VM6();
  BAR();

  int kt0 = 0;
  for (int i = 0; i < NI; ++i, kt0 += 2) {
    READ_A(0, 0); READ_B(0, 0, b0);
    stAU1(1, kt0 + 1);
    BAR(); LGKM0(); PRIO1(); MMA(0, 0, b0); PRIO0(); BAR();
    READ_B(0, 1, b1);
    stAU0(0, kt0 + 2);
    BAR(); LGKM0(); PRIO1(); MMA(0, 1, b1); PRIO0(); BAR();
    READ_A(0, 1);
    stBU0(0, kt0 + 2);
    BAR(); LGKM0(); PRIO1(); MMA(1, 1, b1); PRIO0(); BAR();
    stBU1(0, kt0 + 2);
    BAR(); PRIO1(); MMA(1, 0, b0); PRIO0(); VM6(); BAR();
    READ_A(1, 0); READ_B(1, 0, b0);
    stAU1(0, kt0 + 2);
    BAR(); LGKM0(); PRIO1(); MMA(0, 0, b0); PRIO0(); BAR();
    READ_B(1, 1, b1);
    stAU0(1, kt0 + 3);
    BAR(); LGKM0(); PRIO1(); MMA(0, 1, b1); PRIO0(); BAR();
    READ_A(1, 1);
    stBU0(1, kt0 + 3);
    BAR(); LGKM0(); PRIO1(); MMA(1, 1, b1); PRIO0(); BAR();
    stBU1(1, kt0 + 3);
    BAR(); PRIO1(); MMA(1, 0, b0); PRIO0(); VM6(); BAR();
  }

  READ_A(0, 0); READ_B(0, 0, b0);
  stAU1(1, kt0 + 1);
  BAR(); LGKM0(); PRIO1(); MMA(0, 0, b0); PRIO0(); BAR();
  READ_B(0, 1, b1);
  BAR(); LGKM0(); PRIO1(); MMA(0, 1, b1); PRIO0(); BAR();
  READ_A(0, 1);
  BAR(); LGKM0(); PRIO1(); MMA(1, 1, b1); PRIO0(); BAR();
  BAR(); PRIO1(); MMA(1, 0, b0); PRIO0(); VM0(); BAR();
  READ_A(1, 0); READ_B(1, 0, b0);
  BAR(); LGKM0(); PRIO1(); MMA(0, 0, b0); PRIO0(); BAR();
  READ_B(1, 1, b1);
  BAR(); LGKM0(); PRIO1(); MMA(0, 1, b1); PRIO0(); BAR();
  READ_A(1, 1);
  BAR(); LGKM0(); PRIO1(); MMA(1, 1, b1); PRIO0(); BAR();
  PRIO1(); MMA(1, 0, b0); PRIO0();

  const long rowBase = (long)by * 256 + wm * 128 + kq * 4;
  const int colBase = bx * 256 + wn * 64 + r15;
#pragma unroll
  for (int mf = 0; mf < 8; ++mf) {
#pragma unroll
    for (int nf = 0; nf < 4; ++nf) {
      const int col = colBase + nf * 16;
      const float bv = bias[col];
#pragma unroll
      for (int j = 0; j < 4; ++j) {
        const long row = rowBase + mf * 16 + j;
        Cp[row * LDC + col] = f2bf(fmaxf(acc[mf][nf][j] + bv, 0.f));
      }
    }
  }
}

// ---------------- fused tail: splitK-reduce + gating + dist -> ph -> out ----------------
__global__ __launch_bounds__(256) void k_tail(
    const float* __restrict__ part,  // [8][2048][512] fp32
    const float* __restrict__ biasf, // [512]
    const u16* __restrict__ hg,      // h_all + 12800 (gating cols), row stride 13312
    const float* __restrict__ lw2, const float* __restrict__ lb2,
    const float* __restrict__ bw2, const float* __restrict__ bb2,
    const u16* __restrict__ dw2t,    // [256][512]
    const float* __restrict__ db2,
    const u16* __restrict__ pw1t,    // [256][256]
    const float* __restrict__ pb1,
    const u16* __restrict__ pw2t,    // [256][256]
    const float* __restrict__ pb2,
    float* __restrict__ out) {       // [2048][256] fp32
  __shared__ __align__(16) u16 dhs[16][520];
  __shared__ __align__(16) u16 ds2[16][264];
  __shared__ __align__(16) u16 phs[16][264];
  __shared__ float gl[16];
  const int tid = threadIdx.x;
  const int w = tid >> 6, l = tid & 63;
  const int r = l & 15, kq = l >> 4;
  const int r0 = blockIdx.x * 16;

#pragma unroll
  for (int i = 0; i < 8; ++i) {
    int e = (i * 256 + tid) * 4;
    int row = e >> 9, col = e & 511;
    const float* pp = part + (long)(r0 + row) * 512 + col;
    float4 s = *(const float4*)pp;
#pragma unroll
    for (int k = 1; k < 8; ++k) {
      float4 t = *(const float4*)(pp + (long)k * (2048 * 512));
      s.x += t.x; s.y += t.y; s.z += t.z; s.w += t.w;
    }
    float4 bv = *(const float4*)(biasf + col);
    ushort4 o;
    o.x = f2bf(fmaxf(s.x + bv.x, 0.f));
    o.y = f2bf(fmaxf(s.y + bv.y, 0.f));
    o.z = f2bf(fmaxf(s.z + bv.z, 0.f));
    o.w = f2bf(fmaxf(s.w + bv.w, 0.f));
    *(ushort4*)&dhs[row][col] = o;
  }

#pragma unroll
  for (int j = 0; j < 4; ++j) {
    int rr = w * 4 + j;
    const u16* rowp = hg + (long)(r0 + rr) * 13312;
    float sa = 0.f, sb = 0.f;
#pragma unroll
    for (int jj = 0; jj < 4; ++jj) {
      int i = l * 4 + jj;
      sa += bf2f(rowp[i]) * lw2[i];
      sb += bf2f(rowp[256 + i]) * bw2[i];
    }
#pragma unroll
    for (int off = 32; off > 0; off >>= 1) {
      sa += __shfl_down(sa, off, 64);
      sb += __shfl_down(sb, off, 64);
    }
    if (l == 0) {
      float ga = 1.f / (1.f + expf(-(sa + lb2[0])));
      float gb = 1.f / (1.f + expf(-(sb + bb2[0])));
      gl[rr] = ga * gb;
    }
  }
  __syncthreads();

  v4f acc[4];
#pragma unroll
  for (int n = 0; n < 4; ++n) acc[n] = v4f{0.f, 0.f, 0.f, 0.f};
#pragma unroll 4
  for (int kt = 0; kt < 16; ++kt) {
    v8bf af = *(const v8bf*)&dhs[r][kt * 32 + kq * 8];
#pragma unroll
    for (int n = 0; n < 4; ++n) {
      v8bf bf = *(const v8bf*)(dw2t + (long)(w * 64 + n * 16 + r) * 512 + kt * 32 + kq * 8);
      acc[n] = __builtin_amdgcn_mfma_f32_16x16x32_bf16(af, bf, acc[n], 0, 0, 0);
    }
  }
#pragma unroll
  for (int n = 0; n < 4; ++n) {
    int col = w * 64 + n * 16 + r;
    float bv = db2[col];
#pragma unroll
    for (int j = 0; j < 4; ++j) ds2[kq * 4 + j][col] = f2bf(acc[n][j] + bv);
  }
  __syncthreads();

#pragma unroll
  for (int n = 0; n < 4; ++n) acc[n] = v4f{0.f, 0.f, 0.f, 0.f};
#pragma unroll 4
  for (int kt = 0; kt < 8; ++kt) {
    v8bf af = *(const v8bf*)&ds2[r][kt * 32 + kq * 8];
#pragma unroll
    for (int n = 0; n < 4; ++n) {
      v8bf bf = *(const v8bf*)(pw1t + (long)(w * 64 + n * 16 + r) * 256 + kt * 32 + kq * 8);
      acc[n] = __builtin_amdgcn_mfma_f32_16x16x32_bf16(af, bf, acc[n], 0, 0, 0);
    }
  }
#pragma unroll
  for (int n = 0; n < 4; ++n) {
    int col = w * 64 + n * 16 + r;
    float bv = pb1[col];
#pragma unroll
    for (int j = 0; j < 4; ++j) phs[kq * 4 + j][col] = f2bf(fmaxf(acc[n][j] + bv, 0.f));
  }
  __syncthreads();

#pragma unroll
  for (int n = 0; n < 4; ++n) acc[n] = v4f{0.f, 0.f, 0.f, 0.f};
#pragma unroll 4
  for (int kt = 0; kt < 8; ++kt) {
    v8bf af = *(const v8bf*)&phs[r][kt * 32 + kq * 8];
#pragma unroll
    for (int n = 0; n < 4; ++n) {
      v8bf bf = *(const v8bf*)(pw2t + (long)(w * 64 + n * 16 + r) * 256 + kt * 32 + kq * 8);
      acc[n] = __builtin_amdgcn_mfma_f32_16x16x32_bf16(af, bf, acc[n], 0, 0, 0);
    }
  }
#pragma unroll
  for (int n = 0; n < 4; ++n) {
    int col = w * 64 + n * 16 + r;
    float bv = pb2[col];
#pragma unroll
    for (int j = 0; j < 4; ++j) {
      int row = kq * 4 + j;
      out[(long)(r0 + row) * 256 + col] = (acc[n][j] + bv) * gl[row];
    }
  }
}

extern "C" void kernel_launch(void* const* d_in, const int* in_sizes, int n_in,
                              void* d_out, int out_size, void* d_ws, size_t ws_size,
                              hipStream_t stream) {
  const float* x   = (const float*)d_in[0];
  const float* ew1 = (const float*)d_in[1];
  const float* eb1 = (const float*)d_in[2];
  const float* ew2 = (const float*)d_in[3];
  const float* eb2 = (const float*)d_in[4];
  const float* dw1 = (const float*)d_in[5];
  const float* db1 = (const float*)d_in[6];
  const float* dw2 = (const float*)d_in[7];
  const float* db2 = (const float*)d_in[8];
  const float* lw1 = (const float*)d_in[9];
  const float* lb1 = (const float*)d_in[10];
  const float* lw2 = (const float*)d_in[11];
  const float* lb2 = (const float*)d_in[12];
  const float* bw1 = (const float*)d_in[13];
  const float* bb1 = (const float*)d_in[14];
  const float* bw2 = (const float*)d_in[15];
  const float* bb2 = (const float*)d_in[16];
  const float* pw1 = (const float*)d_in[17];
  const float* pb1 = (const float*)d_in[18];
  const float* pw2 = (const float*)d_in[19];
  const float* pb2 = (const float*)d_in[20];

  const int S = 8;  // proven split-K config (R9/R13)

  char* p = (char*)d_ws;
  auto alloc = [&](size_t bytes) {
    char* q = p;
    p += (bytes + 255) & ~(size_t)255;
    return q;
  };
  u16* xb      = (u16*)alloc((size_t)2048 * 1024 * 2);
  u16* ew1tf   = (u16*)alloc((size_t)13312 * 1024 * 2);  // [ew1t | lw1t | bw1t]
  u16* Wft     = (u16*)alloc((size_t)512 * 12800 * 2);
  u16* dw2t    = (u16*)alloc((size_t)256 * 512 * 2);
  u16* pw1t    = (u16*)alloc((size_t)256 * 256 * 2);
  u16* pw2t    = (u16*)alloc((size_t)256 * 256 * 2);
  float* ebcat = (float*)alloc(13312 * 4);
  float* biasf = (float*)alloc(512 * 4);
  float* part  = (float*)alloc((size_t)S * 2048 * 512 * 4);   // 32 MB
  u16* h_all   = (u16*)alloc((size_t)2048 * 13312 * 2);
  // ew2b + dw1t live inside `part` (used only before the reduce GEMM writes part)
  u16* ew2b    = (u16*)part;
  u16* dw1t    = (u16*)((char*)part + (((size_t)50 * 256 * 256 * 2 + 255) & ~(size_t)255));
  (void)in_sizes; (void)n_in; (void)out_size; (void)ws_size;

  // 1. merged precompute
  k_prep<<<dim3(10292), 256, 0, stream>>>(
      x, ew2, ew1, dw1, dw2, lw1, bw1, pw1, pw2, eb1, lb1, bb1,
      xb, ew2b, ew1tf, dw1t, dw2t, pw1t, pw2t, ebcat);

  // 2. combined: GEMM1 (416 blocks) + Wft GEMM (200 pair-blocks) + biasf (256 pair-blocks)
  k_gemm256<<<dim3(872, 1, 1), 512, 0, stream>>>(
      xb, ew1tf, h_all, ebcat,
      dw1t, ew2b, Wft, eb2, db1, biasf);

  // 3. reduce GEMM (128^2, split-K S=8, z->XCD placement)
  k_gemm_red<<<dim3(512), 256, 0, stream>>>(h_all, Wft, part);

  // 4. fused tail: split-K reduce + gating + dist -> ph -> out (128 blocks x 16 rows)
  k_tail<<<dim3(128), 256, 0, stream>>>(
      part, biasf, h_all + 12800, lw2, lb2, bw2, bb2,
      dw2t, db2, pw1t, pb1, pw2t, pb2, (float*)d_out);
}

// Round 15
// 157.373 us; speedup vs baseline: 1.3510x; 1.0161x over previous
//
#include <hip/hip_runtime.h>
#include <hip/hip_bf16.h>

typedef unsigned short u16;
typedef __attribute__((ext_vector_type(8))) __bf16 v8bf;
typedef __attribute__((ext_vector_type(4))) float v4f;

#define DEVINL __device__ __forceinline__

DEVINL u16 f2bf(float f) {
  union { float f; unsigned u; } v; v.f = f;
  unsigned u = v.u;
  return (u16)((u + 0x7FFFu + ((u >> 16) & 1u)) >> 16);  // RNE
}
DEVINL float bf2f(u16 b) {
  union { unsigned u; float f; } v; v.u = ((unsigned)b) << 16;
  return v.f;
}
DEVINL u16 f2h(float f) {  // f32 -> f16 (RNE)
  _Float16 h = (_Float16)f;
  union { _Float16 h; u16 u; } v; v.h = h;
  return v.u;
}
DEVINL float h2f(u16 b) {
  union { u16 u; _Float16 h; } v; v.u = b;
  return (float)v.h;
}

// async global->LDS, 16B per lane; dest is wave-uniform base + lane*16
DEVINL void async16(const void* g, void* l) {
  __builtin_amdgcn_global_load_lds(
      (__attribute__((address_space(1))) void*)(g),
      (__attribute__((address_space(3))) void*)(l), 16, 0, 0);
}

// ---------------- merged precompute ----------------
DEVINL void f2b_body(const float* __restrict__ src, u16* __restrict__ dst, int base) {
  int i = base + threadIdx.x * 4;
  float4 v = *(const float4*)(src + i);
  unsigned lo = (unsigned)f2bf(v.x) | ((unsigned)f2bf(v.y) << 16);
  unsigned hi = (unsigned)f2bf(v.z) | ((unsigned)f2bf(v.w) << 16);
  uint2 o; o.x = lo; o.y = hi;
  *(uint2*)(dst + i) = o;
}

// 64x64 transpose+convert tile: src fp32 [R][C] -> dst bf16 [C][R]
DEVINL void tr64(u16 (*t)[66], const float* __restrict__ src,
                 u16* __restrict__ dst, int R, int C, int bx, int by) {
  int r0 = by * 64, c0 = bx * 64;
  int tx = threadIdx.x & 15, ty = threadIdx.x >> 4;  // 16x16 threads
#pragma unroll
  for (int i = 0; i < 4; ++i) {
    int rr = ty + i * 16;
    float4 v = *(const float4*)(src + (long)(r0 + rr) * C + c0 + tx * 4);
    u16* d = &t[rr][tx * 4];
    d[0] = f2bf(v.x); d[1] = f2bf(v.y); d[2] = f2bf(v.z); d[3] = f2bf(v.w);
  }
  __syncthreads();
#pragma unroll
  for (int i = 0; i < 4; ++i) {
    int cc = ty + i * 16;
    ushort4 o;
    o.x = t[tx * 4 + 0][cc]; o.y = t[tx * 4 + 1][cc];
    o.z = t[tx * 4 + 2][cc]; o.w = t[tx * 4 + 3][cc];
    *(ushort4*)(dst + (long)(c0 + cc) * R + r0 + tx * 4) = o;
  }
}

__global__ __launch_bounds__(256) void k_prep(
    const float* __restrict__ x, const float* __restrict__ ew2,
    const float* __restrict__ ew1, const float* __restrict__ dw1,
    const float* __restrict__ dw2, const float* __restrict__ lw1,
    const float* __restrict__ bw1, const float* __restrict__ pw1,
    const float* __restrict__ pw2,
    const float* __restrict__ eb1, const float* __restrict__ lb1,
    const float* __restrict__ bb1,
    u16* __restrict__ xb, u16* __restrict__ ew2b, u16* __restrict__ ew1tf,
    u16* __restrict__ dw1t, u16* __restrict__ dw2t,
    u16* __restrict__ pw1t, u16* __restrict__ pw2t,
    float* __restrict__ ebcat) {
  __shared__ u16 tile[64][66];
  int b = blockIdx.x;
  if (b < 2048) { f2b_body(x, xb, b * 1024); return; }
  b -= 2048;
  if (b < 3200) { f2b_body(ew2, ew2b, b * 1024); return; }
  b -= 3200;
  if (b < 3200) {
    int e = b >> 6, t = b & 63;
    tr64(tile, ew1 + (long)e * 1024 * 256, ew1tf + (long)e * 256 * 1024,
         1024, 256, t & 3, t >> 2);
    return;
  }
  b -= 3200;
  if (b < 1600) {
    tr64(tile, dw1, dw1t, 12800, 512, b & 7, b >> 3);
    return;
  }
  b -= 1600;
  if (b < 32) {
    tr64(tile, dw2, dw2t, 512, 256, b & 3, b >> 2);
    return;
  }
  b -= 32;
  if (b < 64) {
    tr64(tile, lw1, ew1tf + (long)12800 * 1024, 1024, 256, b & 3, b >> 2);
    return;
  }
  b -= 64;
  if (b < 64) {
    tr64(tile, bw1, ew1tf + (long)13056 * 1024, 1024, 256, b & 3, b >> 2);
    return;
  }
  b -= 64;
  if (b < 16) {
    tr64(tile, pw1, pw1t, 256, 256, b & 3, b >> 2);
    return;
  }
  b -= 16;
  if (b < 16) {
    tr64(tile, pw2, pw2t, 256, 256, b & 3, b >> 2);
    return;
  }
  b -= 16;
  {
    int i = b * 256 + threadIdx.x;
    float v;
    if (i < 12800) v = eb1[i];
    else if (i < 13056) v = lb1[i - 12800];
    else v = bb1[i - 13056];
    ebcat[i] = v;
  }
}

// ------- 128x128 MFMA GEMM body, compile-time strides (256 lanes, tid-param) -------
// OUT: 0 = bf16, 1 = f32, 2 = f16
template<int LDA, int LDB, int LDC, int K, int OUT>
DEVINL void gemm128_t(int tid, u16* __restrict__ sA, u16* __restrict__ sB,
    int bx, int by, int z,
    const u16* __restrict__ A, long aBatch,
    const u16* __restrict__ B, long bBatch,   // B is Bt: [N][K]
    void* __restrict__ Cp, long cBatch) {
  const int w = tid >> 6, l = tid & 63;
  const u16* Ab = A + z * aBatch + (long)by * 128 * LDA;
  const u16* Bb = B + z * bBatch + (long)bx * 128 * LDB;
  constexpr int ldaB = LDA * 2, ldbB = LDB * 2;
  constexpr int nkt = K / 32;
  const int wm = w >> 1, wn = w & 1;
  const int r = l & 15, kq = l >> 4;

  const int f0 = w * 1024 + l * 16;
  const int f1 = f0 + 4096;
  const int row0 = f0 >> 6, cb0 = f0 & 63;
  const int row1 = f1 >> 6, cb1 = f1 & 63;
  const int seg0 = w * 1024, seg1 = seg0 + 4096;

  v4f acc[4][4];
#pragma unroll
  for (int m = 0; m < 4; ++m)
#pragma unroll
    for (int n = 0; n < 4; ++n) acc[m][n] = v4f{0.f, 0.f, 0.f, 0.f};

  const char* gA = (const char*)Ab;
  const char* gB = (const char*)Bb;

  async16(gA + (long)row0 * ldaB + cb0, (char*)sA + seg0);
  async16(gA + (long)row1 * ldaB + cb1, (char*)sA + seg1);
  async16(gB + (long)row0 * ldbB + cb0, (char*)sB + seg0);
  async16(gB + (long)row1 * ldbB + cb1, (char*)sB + seg1);
  __syncthreads();

  for (int kt = 0; kt < nkt; ++kt) {
    const int cur = kt & 1;
    if (kt + 1 < nkt) {
      const long ko = (long)(kt + 1) * 64;
      async16(gA + ko + (long)row0 * ldaB + cb0, (char*)sA + (cur ^ 1) * 8192 + seg0);
      async16(gA + ko + (long)row1 * ldaB + cb1, (char*)sA + (cur ^ 1) * 8192 + seg1);
      async16(gB + ko + (long)row0 * ldbB + cb0, (char*)sB + (cur ^ 1) * 8192 + seg0);
      async16(gB + ko + (long)row1 * ldbB + cb1, (char*)sB + (cur ^ 1) * 8192 + seg1);
    }
    v8bf af[4], bfr[4];
#pragma unroll
    for (int m = 0; m < 4; ++m)
      af[m] = *(const v8bf*)&sA[cur * 4096 + (wm * 64 + m * 16 + r) * 32 + kq * 8];
#pragma unroll
    for (int n = 0; n < 4; ++n)
      bfr[n] = *(const v8bf*)&sB[cur * 4096 + (wn * 64 + n * 16 + r) * 32 + kq * 8];
#pragma unroll
    for (int m = 0; m < 4; ++m)
#pragma unroll
      for (int n = 0; n < 4; ++n)
        acc[m][n] = __builtin_amdgcn_mfma_f32_16x16x32_bf16(af[m], bfr[n], acc[m][n], 0, 0, 0);
    __syncthreads();
  }

  const long rowBase = (long)by * 128 + wm * 64 + kq * 4;
  const int colBase = bx * 128 + wn * 64 + r;
  float* Cf = (float*)Cp + z * cBatch;
  u16* Ch = (u16*)Cp + z * cBatch;
#pragma unroll
  for (int m = 0; m < 4; ++m) {
#pragma unroll
    for (int n = 0; n < 4; ++n) {
      const int col = colBase + n * 16;
#pragma unroll
      for (int i = 0; i < 4; ++i) {
        const long row = rowBase + m * 16 + i;
        float v = acc[m][n][i];
        const long idx = row * LDC + col;
        if (OUT == 1) Cf[idx] = v;
        else if (OUT == 2) Ch[idx] = f2h(v);
        else Ch[idx] = f2bf(v);
      }
    }
  }
}

// ---- reduce GEMM with z->XCD placement: z = lin & 7 (round-robin dispatch) ----
// All 64 blocks of one K-slice land on one XCD: that slice's B panel (1.6 MB)
// becomes L2-resident; x-neighbors share A panels. [verified R13: -9.3 us]
// fp16 partials: halves split-K traffic; partials (16 MB) fit aggregate L2.
__global__ __launch_bounds__(256) void k_gemm_red(
    const u16* __restrict__ A, const u16* __restrict__ B,
    u16* __restrict__ Cp) {
  __shared__ __align__(16) u16 sA[2 * 4096];
  __shared__ __align__(16) u16 sB[2 * 4096];
  const int lin = blockIdx.x;        // 0..511
  const int z = lin & 7;
  const int xy = lin >> 3;           // 0..63
  const int bx = xy & 3, by = xy >> 2;
  gemm128_t<13312, 12800, 512, 1600, 2>(
      threadIdx.x, sA, sB, bx, by, z,
      A, 1600, B, 1600, Cp, (long)2048 * 512);
}

// ======= combined dispatch: 256^2 8-phase GEMM1 blocks + wft/bias filler blocks =======
// GEMM1 constants: lda=ldb=1024, ldc=13312, K=1024, NX=52, relu, bf16 out.
#define LDS_T(buf, op) (smem + ((buf) * 2 + (op)) * 16384)

#define READ_A(buf, mh) do {                                                   \
  const char* _t = (const char*)LDS_T(buf, 0);                                 \
  _Pragma("unroll") for (int m = 0; m < 4; ++m)                                \
    _Pragma("unroll") for (int kk = 0; kk < 2; ++kk)                           \
      a[m][kk] = *(const v8bf*)(_t +                                           \
        (wm * 128 + (mh) * 64 + m * 16 + r15) * 128 +                          \
        ((kk * 64 + kq * 16) ^ (swr << 4)));                                   \
} while (0)

#define READ_B(buf, nh, br) do {                                               \
  const char* _t = (const char*)LDS_T(buf, 1);                                 \
  _Pragma("unroll") for (int n = 0; n < 2; ++n)                                \
    _Pragma("unroll") for (int kk = 0; kk < 2; ++kk)                           \
      br[n][kk] = *(const v8bf*)(_t +                                          \
        (wn * 64 + (nh) * 32 + n * 16 + r15) * 128 +                          \
        ((kk * 64 + kq * 16) ^ (swr << 4)));                                   \
} while (0)

#define MMA(mh, nh, br) do {                                                   \
  _Pragma("unroll") for (int kk = 0; kk < 2; ++kk)                             \
    _Pragma("unroll") for (int m = 0; m < 4; ++m)                              \
      _Pragma("unroll") for (int n = 0; n < 2; ++n)                            \
        acc[(mh) * 4 + m][(nh) * 2 + n] =                                      \
          __builtin_amdgcn_mfma_f32_16x16x32_bf16(                             \
            a[m][kk], br[n][kk], acc[(mh) * 4 + m][(nh) * 2 + n], 0, 0, 0);    \
} while (0)

#define BAR() __builtin_amdgcn_s_barrier()
#define PRIO1() __builtin_amdgcn_s_setprio(1)
#define PRIO0() __builtin_amdgcn_s_setprio(0)
#define VM6() asm volatile("s_waitcnt vmcnt(6)" ::: "memory")
#define VM0() asm volatile("s_waitcnt vmcnt(0)" ::: "memory")
#define LGKM0() asm volatile("s_waitcnt lgkmcnt(0)" ::: "memory")

__global__ __launch_bounds__(512, 2) void k_gemm256(
    const u16* __restrict__ A,       // xb [2048][1024]
    const u16* __restrict__ B,       // ew1tf [13312][1024]
    u16* __restrict__ Cp,            // h_all, ldc=13312
    const float* __restrict__ bias,  // ebcat
    const u16* __restrict__ dw1t, const u16* __restrict__ ew2b,
    u16* __restrict__ Wft,
    const float* __restrict__ eb2, const float* __restrict__ db1,
    float* __restrict__ biasf) {
  __shared__ __align__(16) u16 smem[2 * 2 * 16384];  // 128 KiB
  constexpr int NGEMM1 = 416, NX = 52, K = 1024, LDAB = 2048, LDC = 13312;

  const int lin = blockIdx.x;
  const int tid = threadIdx.x;

  if (lin >= NGEMM1) {
    int fb = lin - NGEMM1;
    int sub = tid >> 8, t = tid & 255;
    if (fb < 200) {
      int tt = fb * 2 + sub;
      int bx = tt & 1, by = (tt >> 1) & 3, z = tt >> 3;
      u16* base = smem + sub * 16384;
      gemm128_t<12800, 256, 12800, 256, 0>(
          t, base, base + 8192, bx, by, z,
          dw1t, 256, ew2b, (long)256 * 256, Wft, 256);
      return;
    }
    int r = (fb - 200) * 2 + sub;
    const u16* row = dw1t + (long)r * 12800;
    float s = 0.f;
    for (int c = t; c < 1600; c += 256) {
      ushort4 a0 = *(const ushort4*)(row + c * 8);
      ushort4 a1 = *(const ushort4*)(row + c * 8 + 4);
      float4 e0 = *(const float4*)(eb2 + c * 8);
      float4 e1 = *(const float4*)(eb2 + c * 8 + 4);
      s += bf2f(a0.x) * e0.x + bf2f(a0.y) * e0.y + bf2f(a0.z) * e0.z + bf2f(a0.w) * e0.w
         + bf2f(a1.x) * e1.x + bf2f(a1.y) * e1.y + bf2f(a1.z) * e1.z + bf2f(a1.w) * e1.w;
    }
    float* red = (float*)smem + sub * 256;
    red[t] = s;
    __syncthreads();
    for (int off = 128; off > 0; off >>= 1) {
      if (t < off) red[t] += red[t + off];
      __syncthreads();
    }
    if (t == 0) biasf[r] = red[0] + db1[r];
    return;
  }

  // ---------------- GEMM1 path (proven 8-phase schedule, constants folded) ----------------
  const int idx = (lin & 7) * NX + (lin >> 3);
  const int by = idx & 7, bx = idx >> 3;

  const int w = tid >> 6, l = tid & 63;
  const int wm = w >> 2, wn = w & 3;
  const int r15 = l & 15, kq = l >> 4, swr = l & 7;

  const int rl = l >> 3;
  const int scol = ((l & 7) ^ rl) << 4;

  const char* gAs = (const char*)A + ((long)by * 256 + rl) * LDAB + scol;
  const char* gBs = (const char*)B + ((long)bx * 256 + rl) * LDAB + scol;

  auto stA = [&](int buf, int R0, int kt) {
    async16(gAs + (long)R0 * LDAB + (long)kt * 128, (char*)LDS_T(buf, 0) + R0 * 128);
  };
  auto stB = [&](int buf, int R0, int kt) {
    async16(gBs + (long)R0 * LDAB + (long)kt * 128, (char*)LDS_T(buf, 1) + R0 * 128);
  };
  auto stAU0 = [&](int buf, int kt) { stA(buf, w * 8, kt);       stA(buf, 128 + w * 8, kt); };
  auto stAU1 = [&](int buf, int kt) { stA(buf, 64 + w * 8, kt);  stA(buf, 192 + w * 8, kt); };
  auto stBU0 = [&](int buf, int kt) { int R = (w >> 1) * 64 + (w & 1) * 16;      stB(buf, R, kt); stB(buf, R + 8, kt); };
  auto stBU1 = [&](int buf, int kt) { int R = (w >> 1) * 64 + (w & 1) * 16 + 32; stB(buf, R, kt); stB(buf, R + 8, kt); };

  v4f acc[8][4];
#pragma unroll
  for (int m = 0; m < 8; ++m)
#pragma unroll
    for (int n = 0; n < 4; ++n) acc[m][n] = v4f{0.f, 0.f, 0.f, 0.f};
  v8bf a[4][2], b0[2][2], b1[2][2];

  constexpr int NT = K >> 6;        // 16
  constexpr int NI = (NT >> 1) - 1; // 7

  stAU0(0, 0); stBU0(0, 0); stBU1(0, 0); stAU1(0, 0);
  stAU0(1, 1); stBU0(1, 1); stBU1(1, 1);
  VM6();
  BAR();

  int kt0 = 0;
  for (int i = 0; i < NI; ++i, kt0 += 2) {
    READ_A(0, 0); READ_B(0, 0, b0);
    stAU1(1, kt0 + 1);
    BAR(); LGKM0(); PRIO1(); MMA(0, 0, b0); PRIO0(); BAR();
    READ_B(0, 1, b1);
    stAU0(0, kt0 + 2);
    BAR(); LGKM0(); PRIO1(); MMA(0, 1, b1); PRIO0(); BAR();
    READ_A(0, 1);
    stBU0(0, kt0 + 2);
    BAR(); LGKM0(); PRIO1(); MMA(1, 1, b1); PRIO0(); BAR();
    stBU1(0, kt0 + 2);
    BAR(); PRIO1(); MMA(1, 0, b0); PRIO0(); VM6(); BAR();
    READ_A(1, 0); READ_B(1, 0, b0);
    stAU1(0, kt0 + 2);
    BAR(); LGKM0(); PRIO1(); MMA(0, 0, b0); PRIO0(); BAR();
    READ_B(1, 1, b1);
    stAU0(1, kt0 + 3);
    BAR(); LGKM0(); PRIO1(); MMA(0, 1, b1); PRIO0(); BAR();
    READ_A(1, 1);
    stBU0(1, kt0 + 3);
    BAR(); LGKM0(); PRIO1(); MMA(1, 1, b1); PRIO0(); BAR();
    stBU1(1, kt0 + 3);
    BAR(); PRIO1(); MMA(1, 0, b0); PRIO0(); VM6(); BAR();
  }

  READ_A(0, 0); READ_B(0, 0, b0);
  stAU1(1, kt0 + 1);
  BAR(); LGKM0(); PRIO1(); MMA(0, 0, b0); PRIO0(); BAR();
  READ_B(0, 1, b1);
  BAR(); LGKM0(); PRIO1(); MMA(0, 1, b1); PRIO0(); BAR();
  READ_A(0, 1);
  BAR(); LGKM0(); PRIO1(); MMA(1, 1, b1); PRIO0(); BAR();
  BAR(); PRIO1(); MMA(1, 0, b0); PRIO0(); VM0(); BAR();
  READ_A(1, 0); READ_B(1, 0, b0);
  BAR(); LGKM0(); PRIO1(); MMA(0, 0, b0); PRIO0(); BAR();
  READ_B(1, 1, b1);
  BAR(); LGKM0(); PRIO1(); MMA(0, 1, b1); PRIO0(); BAR();
  READ_A(1, 1);
  BAR(); LGKM0(); PRIO1(); MMA(1, 1, b1); PRIO0(); BAR();
  PRIO1(); MMA(1, 0, b0); PRIO0();

  const long rowBase = (long)by * 256 + wm * 128 + kq * 4;
  const int colBase = bx * 256 + wn * 64 + r15;
#pragma unroll
  for (int mf = 0; mf < 8; ++mf) {
#pragma unroll
    for (int nf = 0; nf < 4; ++nf) {
      const int col = colBase + nf * 16;
      const float bv = bias[col];
#pragma unroll
      for (int j = 0; j < 4; ++j) {
        const long row = rowBase + mf * 16 + j;
        Cp[row * LDC + col] = f2bf(fmaxf(acc[mf][nf][j] + bv, 0.f));
      }
    }
  }
}

// ---------------- fused tail: splitK-reduce + gating + dist -> ph -> out ----------------
__global__ __launch_bounds__(256) void k_tail(
    const u16* __restrict__ part,    // [8][2048][512] fp16
    const float* __restrict__ biasf, // [512]
    const u16* __restrict__ hg,      // h_all + 12800 (gating cols), row stride 13312
    const float* __restrict__ lw2, const float* __restrict__ lb2,
    const float* __restrict__ bw2, const float* __restrict__ bb2,
    const u16* __restrict__ dw2t,    // [256][512]
    const float* __restrict__ db2,
    const u16* __restrict__ pw1t,    // [256][256]
    const float* __restrict__ pb1,
    const u16* __restrict__ pw2t,    // [256][256]
    const float* __restrict__ pb2,
    float* __restrict__ out) {       // [2048][256] fp32
  __shared__ __align__(16) u16 dhs[16][520];
  __shared__ __align__(16) u16 ds2[16][264];
  __shared__ __align__(16) u16 phs[16][264];
  __shared__ float gl[16];
  const int tid = threadIdx.x;
  const int w = tid >> 6, l = tid & 63;
  const int r = l & 15, kq = l >> 4;
  const int r0 = blockIdx.x * 16;

#pragma unroll
  for (int i = 0; i < 8; ++i) {
    int e = (i * 256 + tid) * 4;
    int row = e >> 9, col = e & 511;
    const u16* pp = part + (long)(r0 + row) * 512 + col;
    ushort4 t0 = *(const ushort4*)pp;
    float sx = h2f(t0.x), sy = h2f(t0.y), sz = h2f(t0.z), sw = h2f(t0.w);
#pragma unroll
    for (int k = 1; k < 8; ++k) {
      ushort4 tk = *(const ushort4*)(pp + (long)k * (2048 * 512));
      sx += h2f(tk.x); sy += h2f(tk.y); sz += h2f(tk.z); sw += h2f(tk.w);
    }
    float4 bv = *(const float4*)(biasf + col);
    ushort4 o;
    o.x = f2bf(fmaxf(sx + bv.x, 0.f));
    o.y = f2bf(fmaxf(sy + bv.y, 0.f));
    o.z = f2bf(fmaxf(sz + bv.z, 0.f));
    o.w = f2bf(fmaxf(sw + bv.w, 0.f));
    *(ushort4*)&dhs[row][col] = o;
  }

#pragma unroll
  for (int j = 0; j < 4; ++j) {
    int rr = w * 4 + j;
    const u16* rowp = hg + (long)(r0 + rr) * 13312;
    float sa = 0.f, sb = 0.f;
#pragma unroll
    for (int jj = 0; jj < 4; ++jj) {
      int i = l * 4 + jj;
      sa += bf2f(rowp[i]) * lw2[i];
      sb += bf2f(rowp[256 + i]) * bw2[i];
    }
#pragma unroll
    for (int off = 32; off > 0; off >>= 1) {
      sa += __shfl_down(sa, off, 64);
      sb += __shfl_down(sb, off, 64);
    }
    if (l == 0) {
      float ga = 1.f / (1.f + expf(-(sa + lb2[0])));
      float gb = 1.f / (1.f + expf(-(sb + bb2[0])));
      gl[rr] = ga * gb;
    }
  }
  __syncthreads();

  v4f acc[4];
#pragma unroll
  for (int n = 0; n < 4; ++n) acc[n] = v4f{0.f, 0.f, 0.f, 0.f};
#pragma unroll 4
  for (int kt = 0; kt < 16; ++kt) {
    v8bf af = *(const v8bf*)&dhs[r][kt * 32 + kq * 8];
#pragma unroll
    for (int n = 0; n < 4; ++n) {
      v8bf bf = *(const v8bf*)(dw2t + (long)(w * 64 + n * 16 + r) * 512 + kt * 32 + kq * 8);
      acc[n] = __builtin_amdgcn_mfma_f32_16x16x32_bf16(af, bf, acc[n], 0, 0, 0);
    }
  }
#pragma unroll
  for (int n = 0; n < 4; ++n) {
    int col = w * 64 + n * 16 + r;
    float bv = db2[col];
#pragma unroll
    for (int j = 0; j < 4; ++j) ds2[kq * 4 + j][col] = f2bf(acc[n][j] + bv);
  }
  __syncthreads();

#pragma unroll
  for (int n = 0; n < 4; ++n) acc[n] = v4f{0.f, 0.f, 0.f, 0.f};
#pragma unroll 4
  for (int kt = 0; kt < 8; ++kt) {
    v8bf af = *(const v8bf*)&ds2[r][kt * 32 + kq * 8];
#pragma unroll
    for (int n = 0; n < 4; ++n) {
      v8bf bf = *(const v8bf*)(pw1t + (long)(w * 64 + n * 16 + r) * 256 + kt * 32 + kq * 8);
      acc[n] = __builtin_amdgcn_mfma_f32_16x16x32_bf16(af, bf, acc[n], 0, 0, 0);
    }
  }
#pragma unroll
  for (int n = 0; n < 4; ++n) {
    int col = w * 64 + n * 16 + r;
    float bv = pb1[col];
#pragma unroll
    for (int j = 0; j < 4; ++j) phs[kq * 4 + j][col] = f2bf(fmaxf(acc[n][j] + bv, 0.f));
  }
  __syncthreads();

#pragma unroll
  for (int n = 0; n < 4; ++n) acc[n] = v4f{0.f, 0.f, 0.f, 0.f};
#pragma unroll 4
  for (int kt = 0; kt < 8; ++kt) {
    v8bf af = *(const v8bf*)&phs[r][kt * 32 + kq * 8];
#pragma unroll
    for (int n = 0; n < 4; ++n) {
      v8bf bf = *(const v8bf*)(pw2t + (long)(w * 64 + n * 16 + r) * 256 + kt * 32 + kq * 8);
      acc[n] = __builtin_amdgcn_mfma_f32_16x16x32_bf16(af, bf, acc[n], 0, 0, 0);
    }
  }
#pragma unroll
  for (int n = 0; n < 4; ++n) {
    int col = w * 64 + n * 16 + r;
    float bv = pb2[col];
#pragma unroll
    for (int j = 0; j < 4; ++j) {
      int row = kq * 4 + j;
      out[(long)(r0 + row) * 256 + col] = (acc[n][j] + bv) * gl[row];
    }
  }
}

extern "C" void kernel_launch(void* const* d_in, const int* in_sizes, int n_in,
                              void* d_out, int out_size, void* d_ws, size_t ws_size,
                              hipStream_t stream) {
  const float* x   = (const float*)d_in[0];
  const float* ew1 = (const float*)d_in[1];
  const float* eb1 = (const float*)d_in[2];
  const float* ew2 = (const float*)d_in[3];
  const float* eb2 = (const float*)d_in[4];
  const float* dw1 = (const float*)d_in[5];
  const float* db1 = (const float*)d_in[6];
  const float* dw2 = (const float*)d_in[7];
  const float* db2 = (const float*)d_in[8];
  const float* lw1 = (const float*)d_in[9];
  const float* lb1 = (const float*)d_in[10];
  const float* lw2 = (const float*)d_in[11];
  const float* lb2 = (const float*)d_in[12];
  const float* bw1 = (const float*)d_in[13];
  const float* bb1 = (const float*)d_in[14];
  const float* bw2 = (const float*)d_in[15];
  const float* bb2 = (const float*)d_in[16];
  const float* pw1 = (const float*)d_in[17];
  const float* pb1 = (const float*)d_in[18];
  const float* pw2 = (const float*)d_in[19];
  const float* pb2 = (const float*)d_in[20];

  const int S = 8;  // proven split-K config; partials now fp16 (16 MB)

  char* p = (char*)d_ws;
  auto alloc = [&](size_t bytes) {
    char* q = p;
    p += (bytes + 255) & ~(size_t)255;
    return q;
  };
  u16* xb      = (u16*)alloc((size_t)2048 * 1024 * 2);
  u16* ew1tf   = (u16*)alloc((size_t)13312 * 1024 * 2);  // [ew1t | lw1t | bw1t]
  u16* Wft     = (u16*)alloc((size_t)512 * 12800 * 2);
  u16* dw2t    = (u16*)alloc((size_t)256 * 512 * 2);
  u16* pw1t    = (u16*)alloc((size_t)256 * 256 * 2);
  u16* pw2t    = (u16*)alloc((size_t)256 * 256 * 2);
  float* ebcat = (float*)alloc(13312 * 4);
  float* biasf = (float*)alloc(512 * 4);
  u16* ew2b    = (u16*)alloc((size_t)50 * 256 * 256 * 2);   // dedicated (3.3 MB)
  u16* part    = (u16*)alloc((size_t)S * 2048 * 512 * 2);   // fp16 partials, 16 MB
  u16* h_all   = (u16*)alloc((size_t)2048 * 13312 * 2);
  // dw1t (13.1 MB) aliases `part` (16 MB): used only by dispatches 1-2;
  // part is written first by dispatch 3 (reduce). No temporal overlap.
  u16* dw1t    = part;
  (void)in_sizes; (void)n_in; (void)out_size; (void)ws_size;

  // 1. merged precompute
  k_prep<<<dim3(10292), 256, 0, stream>>>(
      x, ew2, ew1, dw1, dw2, lw1, bw1, pw1, pw2, eb1, lb1, bb1,
      xb, ew2b, ew1tf, dw1t, dw2t, pw1t, pw2t, ebcat);

  // 2. combined: GEMM1 (416 blocks) + Wft GEMM (200 pair-blocks) + biasf (256 pair-blocks)
  k_gemm256<<<dim3(872, 1, 1), 512, 0, stream>>>(
      xb, ew1tf, h_all, ebcat,
      dw1t, ew2b, Wft, eb2, db1, biasf);

  // 3. reduce GEMM (128^2, split-K S=8, z->XCD placement, fp16 partials)
  k_gemm_red<<<dim3(512), 256, 0, stream>>>(h_all, Wft, part);

  // 4. fused tail: split-K reduce + gating + dist -> ph -> out (128 blocks x 16 rows)
  k_tail<<<dim3(128), 256, 0, stream>>>(
      part, biasf, h_all + 12800, lw2, lb2, bw2, bb2,
      dw2t, db2, pw1t, pb1, pw2t, pb2, (float*)d_out);
}